// Round 7
// baseline (475.583 us; speedup 1.0000x reference)
//
#include <hip/hip_runtime.h>
#include <hip/hip_bf16.h>

// MoE head: router(top2 of 8) -> compact -> GEMM1+GELU -> GEMM2(split-K) -> combine+residual+LN
// R7: LDS-tiled coalesced weight transpose (was ~90us each, uncoalesced) +
//     3-deep GEMM pipeline (vmcnt(8) steady state, buffers[3], 48KB LDS).
//     Keeps R6's verified XOR bank swizzle (conflicts==0), barrier discipline, setprio.

typedef unsigned short u16;
typedef unsigned int u32;
typedef __attribute__((ext_vector_type(4))) float f32x4;
typedef __attribute__((ext_vector_type(8))) short s16x8;
typedef __attribute__((ext_vector_type(8))) unsigned short u16x8;

#define GLD16(gp, lp) __builtin_amdgcn_global_load_lds( \
    (const __attribute__((address_space(1))) void*)(gp), \
    (__attribute__((address_space(3))) void*)(lp), 16, 0, 0)

__device__ __forceinline__ u16 f2bf(float f) {
    union { float f; u32 u; } v; v.f = f;
    u32 u = v.u;
    return (u16)((u + 0x7fffu + ((u >> 16) & 1u)) >> 16);
}
__device__ __forceinline__ float bf2f(u16 h) {
    union { u32 u; float f; } v; v.u = ((u32)h) << 16; return v.f;
}

// fast GELU: v * sigmoid(1.59577v + 0.0713548v^3)
__device__ __forceinline__ float gelu_f(float v) {
    const float u = v * (0.7978845608f + 0.0356774081f * v * v);
    const float t = __expf(-2.0f * u);
    return v * __builtin_amdgcn_rcpf(1.0f + t);
}

// ---------------- K0: zero counts+cursors (16 ints) ----------------
__global__ void k_init(int* cc) { if (threadIdx.x < 16) cc[threadIdx.x] = 0; }

// ---------------- K1: router (fp32) + x->bf16 convert ----------------
__global__ __launch_bounds__(256) void k_router(
    const float* __restrict__ x, const float* __restrict__ rw, const float* __restrict__ rb,
    u16* __restrict__ xb, int* __restrict__ eidx, float* __restrict__ wgt, int* __restrict__ counts)
{
    const int wav = threadIdx.x >> 6, lane = threadIdx.x & 63;
    const int t = blockIdx.x * 4 + wav;
    const float* xt = x + (size_t)t * 1024;
    float acc[8] = {0.f,0.f,0.f,0.f,0.f,0.f,0.f,0.f};
    #pragma unroll
    for (int c = 0; c < 4; c++) {
        const int base = c * 256 + lane * 4;
        const float4 xv = *(const float4*)(xt + base);
        ushort4 pk;
        pk.x = f2bf(xv.x); pk.y = f2bf(xv.y); pk.z = f2bf(xv.z); pk.w = f2bf(xv.w);
        *(ushort4*)(xb + (size_t)t * 1024 + base) = pk;
        #pragma unroll
        for (int e = 0; e < 8; e++) {
            const float4 wv = *(const float4*)(rw + e * 1024 + base);
            acc[e] += xv.x * wv.x + xv.y * wv.y + xv.z * wv.z + xv.w * wv.w;
        }
    }
    #pragma unroll
    for (int e = 0; e < 8; e++) {
        #pragma unroll
        for (int s = 32; s; s >>= 1) acc[e] += __shfl_xor(acc[e], s);
    }
    if (lane == 0) {
        float v0 = -3e38f, v1 = -3e38f; int i0 = 0, i1 = 0;
        #pragma unroll
        for (int e = 0; e < 8; e++) {
            const float l = acc[e] + rb[e];
            if (l > v0) { v1 = v0; i1 = i0; v0 = l; i0 = e; }
            else if (l > v1) { v1 = l; i1 = e; }
        }
        const float w0 = 1.0f / (1.0f + expf(v1 - v0));
        eidx[2 * t] = i0; eidx[2 * t + 1] = i1;
        wgt[2 * t] = w0; wgt[2 * t + 1] = 1.0f - w0;
        atomicAdd(&counts[i0], 1); atomicAdd(&counts[i1], 1);
    }
}

// ---------------- K2: exclusive prefix of 8 counts ----------------
__global__ void k_offsets(const int* __restrict__ counts, int* __restrict__ offsets) {
    if (threadIdx.x == 0) {
        int s = 0;
        for (int e = 0; e < 8; e++) { offsets[e] = s; s += counts[e]; }
        offsets[8] = s;
    }
}

// ---------------- K3: place assignments into compacted row list ----------------
__global__ __launch_bounds__(256) void k_place(
    const int* __restrict__ eidx, const int* __restrict__ offsets, int* __restrict__ cursors,
    int* __restrict__ rows, int* __restrict__ pos_of)
{
    const int a = blockIdx.x * 256 + threadIdx.x;   // 8192 assignments
    const int e = eidx[a];
    const int pos = offsets[e] + atomicAdd(&cursors[e], 1);
    rows[pos] = a >> 1;
    pos_of[a] = pos;
}

// ---------------- K4: LDS-tiled transpose + fp32->bf16 ----------------
// src [E][R][C] f32 -> dst [E][C][R] bf16 ; grid (C/64, R/64, E), block 256.
// Coalesced float4 reads; transposed scatter into padded LDS; float2 gathers;
// coalesced 16B bf16 writes.
__global__ __launch_bounds__(256) void k_transp(
    const float* __restrict__ src, u16* __restrict__ dst, int R, int C)
{
    __shared__ float tl[64][66];   // [col][row], stride 66 (8B aligned, 2-way banks on b64)
    const int e = blockIdx.z;
    const float* s = src + (size_t)e * R * C;
    u16* d = dst + (size_t)e * R * C;
    const int c0 = blockIdx.x * 64, r0 = blockIdx.y * 64;
    const int tid = threadIdx.x;

    // read: 4 iters, thread -> row (tid>>4)+16j, cols (tid&15)*4 .. +3
    const int rrow = tid >> 4, rc4 = (tid & 15) * 4;
    #pragma unroll
    for (int j = 0; j < 4; j++) {
        const float4 v = *(const float4*)(s + (size_t)(r0 + rrow + j * 16) * C + c0 + rc4);
        tl[rc4 + 0][rrow + j * 16] = v.x;
        tl[rc4 + 1][rrow + j * 16] = v.y;
        tl[rc4 + 2][rrow + j * 16] = v.z;
        tl[rc4 + 3][rrow + j * 16] = v.w;
    }
    __syncthreads();

    // write: 2 iters, thread -> col (tid>>3)+32j, rows (tid&7)*8 .. +7
    const int wcol = tid >> 3, wr8 = (tid & 7) * 8;
    #pragma unroll
    for (int j = 0; j < 2; j++) {
        const int cc = wcol + j * 32;
        u16x8 o;
        #pragma unroll
        for (int k = 0; k < 4; k++) {
            const float2 f = *(const float2*)(&tl[cc][wr8 + k * 2]);
            o[k * 2] = f2bf(f.x);
            o[k * 2 + 1] = f2bf(f.y);
        }
        *(u16x8*)(d + (size_t)(c0 + cc) * R + r0 + wr8) = o;
    }
}

// shared GEMM macros: LDS [3][128][32] bf16 per operand, linear dest;
// source column pre-swizzled (chunk ^= (row>>1)&3), read offset swizzled to match.
#define STAGE_T(b, k0) { \
    char* ad = (char*)At + (b) * 8192 + wav * 1024; \
    char* bd = (char*)Bt + (b) * 8192 + wav * 1024; \
    GLD16(a_src0 + (k0), ad); \
    GLD16(a_src1 + (k0), ad + 4096); \
    GLD16(b_src0 + (k0), bd); \
    GLD16(b_src1 + (k0), bd + 4096); }

#define COMPUTE_T(b) { \
    const u16* Abp = Ab + (b) * 4096; \
    const u16* Bbp = Bb + (b) * 4096; \
    s16x8 af[4], bfr[4]; \
    _Pragma("unroll") \
    for (int i = 0; i < 4; i++) { \
        af[i]  = *(const s16x8*)(Abp + i * 512); \
        bfr[i] = *(const s16x8*)(Bbp + i * 512); \
    } \
    __builtin_amdgcn_s_setprio(1); \
    _Pragma("unroll") \
    for (int mi = 0; mi < 4; mi++) \
        _Pragma("unroll") \
        for (int ni = 0; ni < 4; ni++) \
            acc[mi][ni] = __builtin_amdgcn_mfma_f32_16x16x32_bf16(af[mi], bfr[ni], acc[mi][ni], 0, 0, 0); \
    __builtin_amdgcn_s_setprio(0); }

#define VMCNT8 asm volatile("s_waitcnt vmcnt(8)" ::: "memory")
#define VMCNT4 asm volatile("s_waitcnt vmcnt(4)" ::: "memory")
#define VMCNT0 asm volatile("s_waitcnt vmcnt(0)" ::: "memory")
#define BAR __builtin_amdgcn_s_barrier()

// 3-deep pipelined K-loop: stage t+2 while computing t; vmcnt(8) steady state.
#define KLOOP(NSTEP) { \
    STAGE_T(0, 0); \
    STAGE_T(1, 32); \
    int cur = 0, nxt = 2; \
    for (int t = 0; t < (NSTEP); ++t) { \
        if (t + 2 < (NSTEP)) { \
            STAGE_T(nxt, (t + 2) * 32); \
            nxt = (nxt == 2) ? 0 : nxt + 1; \
            VMCNT8; \
        } else if (t + 1 < (NSTEP)) { VMCNT4; } else { VMCNT0; } \
        BAR; \
        COMPUTE_T(cur); \
        cur = (cur == 2) ? 0 : cur + 1; \
        BAR; \
    } }

// ---------------- K5: grouped GEMM1 + bias + fast GELU -> h (bf16) ----------------
// 8192 blocks flat; swz -> (e, x=n-tile of 32, y=row-tile of 32, y fastest)
__global__ __launch_bounds__(256, 3) void k_gemm1(
    const u16* __restrict__ xb, const u16* __restrict__ W1t, const float* __restrict__ b1,
    u16* __restrict__ hbuf, const int* __restrict__ rows, const int* __restrict__ offsets)
{
    const int fid = blockIdx.x;
    const int swz = (fid & 7) * 1024 + (fid >> 3);   // bijective, nwg=8192
    const int y = swz & 31, xx = (swz >> 5) & 31, e = swz >> 10;

    const int off = offsets[e], cnt = offsets[e + 1] - off;
    const int row0 = y * 128;
    if (row0 >= cnt) return;
    const int n0 = xx * 128;
    const int tid = threadIdx.x;
    const int lane = tid & 63, wav = tid >> 6, lane15 = lane & 15;

    __shared__ u16 At[3][128][32];
    __shared__ u16 Bt[3][128][32];

    const int ar0 = tid >> 2;
    const int cl8 = (((tid & 3) ^ ((tid >> 3) & 3))) * 8;   // swizzled source chunk
    const int t0 = rows[off + min(row0 + ar0, cnt - 1)];
    const int t1 = rows[off + min(row0 + ar0 + 64, cnt - 1)];
    const u16* a_src0 = xb + (size_t)t0 * 1024 + cl8;
    const u16* a_src1 = xb + (size_t)t1 * 1024 + cl8;
    const u16* b_src0 = W1t + ((size_t)e * 4096 + n0 + ar0) * 1024 + cl8;
    const u16* b_src1 = b_src0 + (size_t)64 * 1024;

    f32x4 acc[4][4] = {};
    const int wr = wav >> 1, wc = wav & 1;
    const int koff = ((lane >> 4) ^ ((lane >> 1) & 3)) * 8;  // swizzled read chunk
    const u16* Ab = &At[0][wr * 64 + lane15][koff];
    const u16* Bb = &Bt[0][wc * 64 + lane15][koff];

    KLOOP(32);

    const int rb4 = (lane >> 4) * 4;
    const int colbase = n0 + wc * 64 + lane15;
    float bias[4];
    #pragma unroll
    for (int ni = 0; ni < 4; ni++) bias[ni] = b1[e * 4096 + colbase + ni * 16];
    #pragma unroll
    for (int mi = 0; mi < 4; mi++) {
        #pragma unroll
        for (int j = 0; j < 4; j++) {
            const int lrow = wr * 64 + mi * 16 + rb4 + j;
            if (row0 + lrow < cnt) {
                const size_t gr = (size_t)(off + row0 + lrow);
                #pragma unroll
                for (int ni = 0; ni < 4; ni++) {
                    const float v = acc[mi][ni][j] + bias[ni];
                    hbuf[gr * 4096 + colbase + ni * 16] = f2bf(gelu_f(v));
                }
            }
        }
    }
}

// ---------------- K6: grouped GEMM2 (split-K x2) + bias -> y0/y1 (bf16) ----------------
// 4096 blocks flat; swz -> (z=e*2+kh, x=n-tile of 8, y=row-tile of 32, y fastest)
__global__ __launch_bounds__(256, 3) void k_gemm2(
    const u16* __restrict__ hbuf, const u16* __restrict__ W2t, const float* __restrict__ b2,
    u16* __restrict__ y0b, u16* __restrict__ y1b, const int* __restrict__ offsets)
{
    const int fid = blockIdx.x;
    const int swz = (fid & 7) * 512 + (fid >> 3);    // bijective, nwg=4096
    const int y = swz & 31, xx = (swz >> 5) & 7, z = swz >> 8;
    const int e = z >> 1, kh = z & 1;

    const int off = offsets[e], cnt = offsets[e + 1] - off;
    const int row0 = y * 128;
    if (row0 >= cnt) return;
    const int n0 = xx * 128;
    const int tid = threadIdx.x;
    const int lane = tid & 63, wav = tid >> 6, lane15 = lane & 15;
    const int kbase = kh * 2048;

    __shared__ u16 At[3][128][32];
    __shared__ u16 Bt[3][128][32];

    const int ar0 = tid >> 2;
    const int cl8 = (((tid & 3) ^ ((tid >> 3) & 3))) * 8;
    const u16* a_src0 = hbuf + (size_t)(off + min(row0 + ar0, cnt - 1)) * 4096 + kbase + cl8;
    const u16* a_src1 = hbuf + (size_t)(off + min(row0 + ar0 + 64, cnt - 1)) * 4096 + kbase + cl8;
    const u16* b_src0 = W2t + ((size_t)e * 1024 + n0 + ar0) * 4096 + kbase + cl8;
    const u16* b_src1 = b_src0 + (size_t)64 * 4096;

    f32x4 acc[4][4] = {};
    const int wr = wav >> 1, wc = wav & 1;
    const int koff = ((lane >> 4) ^ ((lane >> 1) & 3)) * 8;
    const u16* Ab = &At[0][wr * 64 + lane15][koff];
    const u16* Bb = &Bt[0][wc * 64 + lane15][koff];

    KLOOP(64);

    u16* yy = kh ? y1b : y0b;
    const int rb4 = (lane >> 4) * 4;
    const int colbase = n0 + wc * 64 + lane15;
    float bias[4];
    #pragma unroll
    for (int ni = 0; ni < 4; ni++) bias[ni] = kh ? 0.f : b2[e * 1024 + colbase + ni * 16];
    #pragma unroll
    for (int mi = 0; mi < 4; mi++) {
        #pragma unroll
        for (int j = 0; j < 4; j++) {
            const int lrow = wr * 64 + mi * 16 + rb4 + j;
            if (row0 + lrow < cnt) {
                const size_t gr = (size_t)(off + row0 + lrow);
                #pragma unroll
                for (int ni = 0; ni < 4; ni++)
                    yy[gr * 1024 + colbase + ni * 16] = f2bf(acc[mi][ni][j] + bias[ni]);
            }
        }
    }
}

// ---------------- K7: combine (w0*(y0+y1) + residual) + LayerNorm ----------------
__global__ __launch_bounds__(256) void k_combine(
    const float* __restrict__ x, const u16* __restrict__ y0b, const u16* __restrict__ y1b,
    const int* __restrict__ pos_of, const float* __restrict__ wgt,
    const float* __restrict__ gamma, const float* __restrict__ beta,
    float* __restrict__ out)
{
    const int t = blockIdx.x;
    const int tid = threadIdx.x;
    const int p0 = pos_of[2 * t], p1 = pos_of[2 * t + 1];
    const float w0 = wgt[2 * t], w1 = wgt[2 * t + 1];
    const int j4 = tid * 4;
    const float4 xv = *(const float4*)(x + (size_t)t * 1024 + j4);
    const ushort4 ua0 = *(const ushort4*)(y0b + (size_t)p0 * 1024 + j4);
    const ushort4 ub0 = *(const ushort4*)(y1b + (size_t)p0 * 1024 + j4);
    const ushort4 ua1 = *(const ushort4*)(y0b + (size_t)p1 * 1024 + j4);
    const ushort4 ub1 = *(const ushort4*)(y1b + (size_t)p1 * 1024 + j4);
    float a0 = xv.x + w0 * (bf2f(ua0.x) + bf2f(ub0.x)) + w1 * (bf2f(ua1.x) + bf2f(ub1.x));
    float a1 = xv.y + w0 * (bf2f(ua0.y) + bf2f(ub0.y)) + w1 * (bf2f(ua1.y) + bf2f(ub1.y));
    float a2 = xv.z + w0 * (bf2f(ua0.z) + bf2f(ub0.z)) + w1 * (bf2f(ua1.z) + bf2f(ub1.z));
    float a3 = xv.w + w0 * (bf2f(ua0.w) + bf2f(ub0.w)) + w1 * (bf2f(ua1.w) + bf2f(ub1.w));
    float s = a0 + a1 + a2 + a3;
    float q = a0 * a0 + a1 * a1 + a2 * a2 + a3 * a3;
    #pragma unroll
    for (int o = 32; o; o >>= 1) { s += __shfl_xor(s, o); q += __shfl_xor(q, o); }
    __shared__ float ls[4], lq[4];
    const int wav = tid >> 6, lane = tid & 63;
    if (lane == 0) { ls[wav] = s; lq[wav] = q; }
    __syncthreads();
    s = ls[0] + ls[1] + ls[2] + ls[3];
    q = lq[0] + lq[1] + lq[2] + lq[3];
    const float mu = s * (1.0f / 1024.0f);
    const float var = q * (1.0f / 1024.0f) - mu * mu;
    const float rs = rsqrtf(var + 1e-5f);
    const float4 g = *(const float4*)(gamma + j4);
    const float4 b = *(const float4*)(beta + j4);
    float4 o4;
    o4.x = (a0 - mu) * rs * g.x + b.x;
    o4.y = (a1 - mu) * rs * g.y + b.y;
    o4.z = (a2 - mu) * rs * g.z + b.z;
    o4.w = (a3 - mu) * rs * g.w + b.w;
    *(float4*)(out + (size_t)t * 1024 + j4) = o4;
}

extern "C" void kernel_launch(void* const* d_in, const int* in_sizes, int n_in,
                              void* d_out, int out_size, void* d_ws, size_t ws_size,
                              hipStream_t stream) {
    const float* x     = (const float*)d_in[0];   // [2,2048,1024]
    const float* rw    = (const float*)d_in[1];   // [8,1024]
    const float* rb    = (const float*)d_in[2];   // [8]
    const float* W1    = (const float*)d_in[3];   // [8,1024,4096]
    const float* b1    = (const float*)d_in[4];   // [8,4096]
    const float* W2    = (const float*)d_in[5];   // [8,4096,1024]
    const float* b2    = (const float*)d_in[6];   // [8,1024]
    const float* gamma = (const float*)d_in[7];   // [1024]
    const float* beta  = (const float*)d_in[8];   // [1024]
    float* out = (float*)d_out;

    // workspace carve (256B aligned)
    char* p = (char*)d_ws;
    auto alloc = [&](size_t bytes) { char* r = p; p += (bytes + 255) & ~(size_t)255; return r; };
    int*   counts  = (int*)alloc(16 * sizeof(int));      // counts[0..7], cursors[8..15]
    int*   cursors = counts + 8;
    int*   offsets = (int*)alloc(9 * sizeof(int));
    int*   eidx    = (int*)alloc(8192 * sizeof(int));
    float* wgt     = (float*)alloc(8192 * sizeof(float));
    int*   pos_of  = (int*)alloc(8192 * sizeof(int));
    int*   rows    = (int*)alloc(8192 * sizeof(int));
    u16*   xb      = (u16*)alloc((size_t)4096 * 1024 * 2);
    u16*   W1t     = (u16*)alloc((size_t)8 * 4096 * 1024 * 2);   // 64MB; dead after gemm1
    u16*   W2t     = (u16*)alloc((size_t)8 * 1024 * 4096 * 2);
    u16*   hbuf    = (u16*)alloc((size_t)8192 * 4096 * 2);
    // y0/y1 (bf16, 16MB each) alias W1t (dead after gemm1)
    u16* y0b = W1t;
    u16* y1b = W1t + (size_t)8192 * 1024;

    hipLaunchKernelGGL(k_init, dim3(1), dim3(64), 0, stream, counts);
    hipLaunchKernelGGL(k_router, dim3(1024), dim3(256), 0, stream, x, rw, rb, xb, eidx, wgt, counts);
    hipLaunchKernelGGL(k_offsets, dim3(1), dim3(64), 0, stream, counts, offsets);
    hipLaunchKernelGGL(k_place, dim3(32), dim3(256), 0, stream, eidx, offsets, cursors, rows, pos_of);
    // W1 [E][1024][4096] -> W1t [E][4096][1024]
    hipLaunchKernelGGL(k_transp, dim3(64, 16, 8), dim3(256), 0, stream, W1, W1t, 1024, 4096);
    // W2 [E][4096][1024] -> W2t [E][1024][4096]
    hipLaunchKernelGGL(k_transp, dim3(16, 64, 8), dim3(256), 0, stream, W2, W2t, 4096, 1024);
    hipLaunchKernelGGL(k_gemm1, dim3(8192), dim3(256), 0, stream, xb, W1t, b1, hbuf, rows, offsets);
    hipLaunchKernelGGL(k_gemm2, dim3(4096), dim3(256), 0, stream, hbuf, W2t, b2, y0b, y1b, offsets);
    hipLaunchKernelGGL(k_combine, dim3(4096), dim3(256), 0, stream, x, y0b, y1b, pos_of, wgt, gamma, beta, out);
}

// Round 8
// 453.238 us; speedup vs baseline: 1.0493x; 1.0493x over previous
//
#include <hip/hip_runtime.h>
#include <hip/hip_bf16.h>

// MoE head: router(top2 of 8) -> compact -> GEMM1+GELU -> GEMM2(split-K) -> combine+residual+LN
// R8: GEMMs reverted to R6 exactly (2-deep dbuf, vmcnt(4), 32KB LDS, zero-conflict swizzle,
//     setprio, bounds(256,4)) — R7's 3-deep pipeline regressed both GEMMs (-21us gemm1).
//     Keeps R7's LDS-tiled coalesced weight transpose.

typedef unsigned short u16;
typedef unsigned int u32;
typedef __attribute__((ext_vector_type(4))) float f32x4;
typedef __attribute__((ext_vector_type(8))) short s16x8;
typedef __attribute__((ext_vector_type(8))) unsigned short u16x8;

#define GLD16(gp, lp) __builtin_amdgcn_global_load_lds( \
    (const __attribute__((address_space(1))) void*)(gp), \
    (__attribute__((address_space(3))) void*)(lp), 16, 0, 0)

__device__ __forceinline__ u16 f2bf(float f) {
    union { float f; u32 u; } v; v.f = f;
    u32 u = v.u;
    return (u16)((u + 0x7fffu + ((u >> 16) & 1u)) >> 16);
}
__device__ __forceinline__ float bf2f(u16 h) {
    union { u32 u; float f; } v; v.u = ((u32)h) << 16; return v.f;
}

// fast GELU: v * sigmoid(1.59577v + 0.0713548v^3)
__device__ __forceinline__ float gelu_f(float v) {
    const float u = v * (0.7978845608f + 0.0356774081f * v * v);
    const float t = __expf(-2.0f * u);
    return v * __builtin_amdgcn_rcpf(1.0f + t);
}

// ---------------- K0: zero counts+cursors (16 ints) ----------------
__global__ void k_init(int* cc) { if (threadIdx.x < 16) cc[threadIdx.x] = 0; }

// ---------------- K1: router (fp32) + x->bf16 convert ----------------
__global__ __launch_bounds__(256) void k_router(
    const float* __restrict__ x, const float* __restrict__ rw, const float* __restrict__ rb,
    u16* __restrict__ xb, int* __restrict__ eidx, float* __restrict__ wgt, int* __restrict__ counts)
{
    const int wav = threadIdx.x >> 6, lane = threadIdx.x & 63;
    const int t = blockIdx.x * 4 + wav;
    const float* xt = x + (size_t)t * 1024;
    float acc[8] = {0.f,0.f,0.f,0.f,0.f,0.f,0.f,0.f};
    #pragma unroll
    for (int c = 0; c < 4; c++) {
        const int base = c * 256 + lane * 4;
        const float4 xv = *(const float4*)(xt + base);
        ushort4 pk;
        pk.x = f2bf(xv.x); pk.y = f2bf(xv.y); pk.z = f2bf(xv.z); pk.w = f2bf(xv.w);
        *(ushort4*)(xb + (size_t)t * 1024 + base) = pk;
        #pragma unroll
        for (int e = 0; e < 8; e++) {
            const float4 wv = *(const float4*)(rw + e * 1024 + base);
            acc[e] += xv.x * wv.x + xv.y * wv.y + xv.z * wv.z + xv.w * wv.w;
        }
    }
    #pragma unroll
    for (int e = 0; e < 8; e++) {
        #pragma unroll
        for (int s = 32; s; s >>= 1) acc[e] += __shfl_xor(acc[e], s);
    }
    if (lane == 0) {
        float v0 = -3e38f, v1 = -3e38f; int i0 = 0, i1 = 0;
        #pragma unroll
        for (int e = 0; e < 8; e++) {
            const float l = acc[e] + rb[e];
            if (l > v0) { v1 = v0; i1 = i0; v0 = l; i0 = e; }
            else if (l > v1) { v1 = l; i1 = e; }
        }
        const float w0 = 1.0f / (1.0f + expf(v1 - v0));
        eidx[2 * t] = i0; eidx[2 * t + 1] = i1;
        wgt[2 * t] = w0; wgt[2 * t + 1] = 1.0f - w0;
        atomicAdd(&counts[i0], 1); atomicAdd(&counts[i1], 1);
    }
}

// ---------------- K2: exclusive prefix of 8 counts ----------------
__global__ void k_offsets(const int* __restrict__ counts, int* __restrict__ offsets) {
    if (threadIdx.x == 0) {
        int s = 0;
        for (int e = 0; e < 8; e++) { offsets[e] = s; s += counts[e]; }
        offsets[8] = s;
    }
}

// ---------------- K3: place assignments into compacted row list ----------------
__global__ __launch_bounds__(256) void k_place(
    const int* __restrict__ eidx, const int* __restrict__ offsets, int* __restrict__ cursors,
    int* __restrict__ rows, int* __restrict__ pos_of)
{
    const int a = blockIdx.x * 256 + threadIdx.x;   // 8192 assignments
    const int e = eidx[a];
    const int pos = offsets[e] + atomicAdd(&cursors[e], 1);
    rows[pos] = a >> 1;
    pos_of[a] = pos;
}

// ---------------- K4: LDS-tiled transpose + fp32->bf16 ----------------
// src [E][R][C] f32 -> dst [E][C][R] bf16 ; grid (C/64, R/64, E), block 256.
__global__ __launch_bounds__(256) void k_transp(
    const float* __restrict__ src, u16* __restrict__ dst, int R, int C)
{
    __shared__ float tl[64][66];   // [col][row]
    const int e = blockIdx.z;
    const float* s = src + (size_t)e * R * C;
    u16* d = dst + (size_t)e * R * C;
    const int c0 = blockIdx.x * 64, r0 = blockIdx.y * 64;
    const int tid = threadIdx.x;

    const int rrow = tid >> 4, rc4 = (tid & 15) * 4;
    #pragma unroll
    for (int j = 0; j < 4; j++) {
        const float4 v = *(const float4*)(s + (size_t)(r0 + rrow + j * 16) * C + c0 + rc4);
        tl[rc4 + 0][rrow + j * 16] = v.x;
        tl[rc4 + 1][rrow + j * 16] = v.y;
        tl[rc4 + 2][rrow + j * 16] = v.z;
        tl[rc4 + 3][rrow + j * 16] = v.w;
    }
    __syncthreads();

    const int wcol = tid >> 3, wr8 = (tid & 7) * 8;
    #pragma unroll
    for (int j = 0; j < 2; j++) {
        const int cc = wcol + j * 32;
        u16x8 o;
        #pragma unroll
        for (int k = 0; k < 4; k++) {
            const float2 f = *(const float2*)(&tl[cc][wr8 + k * 2]);
            o[k * 2] = f2bf(f.x);
            o[k * 2 + 1] = f2bf(f.y);
        }
        *(u16x8*)(d + (size_t)(c0 + cc) * R + r0 + wr8) = o;
    }
}

// shared GEMM macros: LDS [2][128][32] bf16 per operand, linear dest;
// source column pre-swizzled (chunk ^= (row>>1)&3), read offset swizzled to match.
#define STAGE_T(b, k0) { \
    char* ad = (char*)At + (b) * 8192 + wav * 1024; \
    char* bd = (char*)Bt + (b) * 8192 + wav * 1024; \
    GLD16(a_src0 + (k0), ad); \
    GLD16(a_src1 + (k0), ad + 4096); \
    GLD16(b_src0 + (k0), bd); \
    GLD16(b_src1 + (k0), bd + 4096); }

#define COMPUTE_T(b) { \
    const u16* Abp = Ab + (b) * 4096; \
    const u16* Bbp = Bb + (b) * 4096; \
    s16x8 af[4], bfr[4]; \
    _Pragma("unroll") \
    for (int i = 0; i < 4; i++) { \
        af[i]  = *(const s16x8*)(Abp + i * 512); \
        bfr[i] = *(const s16x8*)(Bbp + i * 512); \
    } \
    __builtin_amdgcn_s_setprio(1); \
    _Pragma("unroll") \
    for (int mi = 0; mi < 4; mi++) \
        _Pragma("unroll") \
        for (int ni = 0; ni < 4; ni++) \
            acc[mi][ni] = __builtin_amdgcn_mfma_f32_16x16x32_bf16(af[mi], bfr[ni], acc[mi][ni], 0, 0, 0); \
    __builtin_amdgcn_s_setprio(0); }

#define VMCNT4 asm volatile("s_waitcnt vmcnt(4)" ::: "memory")
#define VMCNT0 asm volatile("s_waitcnt vmcnt(0)" ::: "memory")
#define BAR __builtin_amdgcn_s_barrier()

// ---------------- K5: grouped GEMM1 + bias + fast GELU -> h (bf16) ----------------
// 8192 blocks flat; swz -> (e, x=n-tile of 32, y=row-tile of 32, y fastest)
__global__ __launch_bounds__(256, 4) void k_gemm1(
    const u16* __restrict__ xb, const u16* __restrict__ W1t, const float* __restrict__ b1,
    u16* __restrict__ hbuf, const int* __restrict__ rows, const int* __restrict__ offsets)
{
    const int fid = blockIdx.x;
    const int swz = (fid & 7) * 1024 + (fid >> 3);   // bijective, nwg=8192
    const int y = swz & 31, xx = (swz >> 5) & 31, e = swz >> 10;

    const int off = offsets[e], cnt = offsets[e + 1] - off;
    const int row0 = y * 128;
    if (row0 >= cnt) return;
    const int n0 = xx * 128;
    const int tid = threadIdx.x;
    const int lane = tid & 63, wav = tid >> 6, lane15 = lane & 15;

    __shared__ u16 At[2][128][32];
    __shared__ u16 Bt[2][128][32];

    const int ar0 = tid >> 2;
    const int cl8 = (((tid & 3) ^ ((tid >> 3) & 3))) * 8;   // swizzled source chunk
    const int t0 = rows[off + min(row0 + ar0, cnt - 1)];
    const int t1 = rows[off + min(row0 + ar0 + 64, cnt - 1)];
    const u16* a_src0 = xb + (size_t)t0 * 1024 + cl8;
    const u16* a_src1 = xb + (size_t)t1 * 1024 + cl8;
    const u16* b_src0 = W1t + ((size_t)e * 4096 + n0 + ar0) * 1024 + cl8;
    const u16* b_src1 = b_src0 + (size_t)64 * 1024;

    f32x4 acc[4][4] = {};
    const int wr = wav >> 1, wc = wav & 1;
    const int koff = ((lane >> 4) ^ ((lane >> 1) & 3)) * 8;  // swizzled read chunk
    const u16* Ab = &At[0][wr * 64 + lane15][koff];
    const u16* Bb = &Bt[0][wc * 64 + lane15][koff];

    STAGE_T(0, 0);
    int b = 0;
    for (int k0 = 32; k0 < 1024; k0 += 32) {
        STAGE_T(b ^ 1, k0);
        VMCNT4;             // current buffer's 4 loads landed (next 4 stay in flight)
        BAR;
        COMPUTE_T(b);
        BAR;                // all waves done reading buffer b
        b ^= 1;
    }
    VMCNT0;
    BAR;
    COMPUTE_T(b);

    const int rb4 = (lane >> 4) * 4;
    const int colbase = n0 + wc * 64 + lane15;
    float bias[4];
    #pragma unroll
    for (int ni = 0; ni < 4; ni++) bias[ni] = b1[e * 4096 + colbase + ni * 16];
    #pragma unroll
    for (int mi = 0; mi < 4; mi++) {
        #pragma unroll
        for (int j = 0; j < 4; j++) {
            const int lrow = wr * 64 + mi * 16 + rb4 + j;
            if (row0 + lrow < cnt) {
                const size_t gr = (size_t)(off + row0 + lrow);
                #pragma unroll
                for (int ni = 0; ni < 4; ni++) {
                    const float v = acc[mi][ni][j] + bias[ni];
                    hbuf[gr * 4096 + colbase + ni * 16] = f2bf(gelu_f(v));
                }
            }
        }
    }
}

// ---------------- K6: grouped GEMM2 (split-K x2) + bias -> y0/y1 (bf16) ----------------
// 4096 blocks flat; swz -> (z=e*2+kh, x=n-tile of 8, y=row-tile of 32, y fastest)
__global__ __launch_bounds__(256, 4) void k_gemm2(
    const u16* __restrict__ hbuf, const u16* __restrict__ W2t, const float* __restrict__ b2,
    u16* __restrict__ y0b, u16* __restrict__ y1b, const int* __restrict__ offsets)
{
    const int fid = blockIdx.x;
    const int swz = (fid & 7) * 512 + (fid >> 3);    // bijective, nwg=4096
    const int y = swz & 31, xx = (swz >> 5) & 7, z = swz >> 8;
    const int e = z >> 1, kh = z & 1;

    const int off = offsets[e], cnt = offsets[e + 1] - off;
    const int row0 = y * 128;
    if (row0 >= cnt) return;
    const int n0 = xx * 128;
    const int tid = threadIdx.x;
    const int lane = tid & 63, wav = tid >> 6, lane15 = lane & 15;
    const int kbase = kh * 2048;

    __shared__ u16 At[2][128][32];
    __shared__ u16 Bt[2][128][32];

    const int ar0 = tid >> 2;
    const int cl8 = (((tid & 3) ^ ((tid >> 3) & 3))) * 8;
    const u16* a_src0 = hbuf + (size_t)(off + min(row0 + ar0, cnt - 1)) * 4096 + kbase + cl8;
    const u16* a_src1 = hbuf + (size_t)(off + min(row0 + ar0 + 64, cnt - 1)) * 4096 + kbase + cl8;
    const u16* b_src0 = W2t + ((size_t)e * 1024 + n0 + ar0) * 4096 + kbase + cl8;
    const u16* b_src1 = b_src0 + (size_t)64 * 4096;

    f32x4 acc[4][4] = {};
    const int wr = wav >> 1, wc = wav & 1;
    const int koff = ((lane >> 4) ^ ((lane >> 1) & 3)) * 8;
    const u16* Ab = &At[0][wr * 64 + lane15][koff];
    const u16* Bb = &Bt[0][wc * 64 + lane15][koff];

    STAGE_T(0, 0);
    int b = 0;
    for (int k0 = 32; k0 < 2048; k0 += 32) {
        STAGE_T(b ^ 1, k0);
        VMCNT4;
        BAR;
        COMPUTE_T(b);
        BAR;
        b ^= 1;
    }
    VMCNT0;
    BAR;
    COMPUTE_T(b);

    u16* yy = kh ? y1b : y0b;
    const int rb4 = (lane >> 4) * 4;
    const int colbase = n0 + wc * 64 + lane15;
    float bias[4];
    #pragma unroll
    for (int ni = 0; ni < 4; ni++) bias[ni] = kh ? 0.f : b2[e * 1024 + colbase + ni * 16];
    #pragma unroll
    for (int mi = 0; mi < 4; mi++) {
        #pragma unroll
        for (int j = 0; j < 4; j++) {
            const int lrow = wr * 64 + mi * 16 + rb4 + j;
            if (row0 + lrow < cnt) {
                const size_t gr = (size_t)(off + row0 + lrow);
                #pragma unroll
                for (int ni = 0; ni < 4; ni++)
                    yy[gr * 1024 + colbase + ni * 16] = f2bf(acc[mi][ni][j] + bias[ni]);
            }
        }
    }
}

// ---------------- K7: combine (w0*(y0+y1) + residual) + LayerNorm ----------------
__global__ __launch_bounds__(256) void k_combine(
    const float* __restrict__ x, const u16* __restrict__ y0b, const u16* __restrict__ y1b,
    const int* __restrict__ pos_of, const float* __restrict__ wgt,
    const float* __restrict__ gamma, const float* __restrict__ beta,
    float* __restrict__ out)
{
    const int t = blockIdx.x;
    const int tid = threadIdx.x;
    const int p0 = pos_of[2 * t], p1 = pos_of[2 * t + 1];
    const float w0 = wgt[2 * t], w1 = wgt[2 * t + 1];
    const int j4 = tid * 4;
    const float4 xv = *(const float4*)(x + (size_t)t * 1024 + j4);
    const ushort4 ua0 = *(const ushort4*)(y0b + (size_t)p0 * 1024 + j4);
    const ushort4 ub0 = *(const ushort4*)(y1b + (size_t)p0 * 1024 + j4);
    const ushort4 ua1 = *(const ushort4*)(y0b + (size_t)p1 * 1024 + j4);
    const ushort4 ub1 = *(const ushort4*)(y1b + (size_t)p1 * 1024 + j4);
    float a0 = xv.x + w0 * (bf2f(ua0.x) + bf2f(ub0.x)) + w1 * (bf2f(ua1.x) + bf2f(ub1.x));
    float a1 = xv.y + w0 * (bf2f(ua0.y) + bf2f(ub0.y)) + w1 * (bf2f(ua1.y) + bf2f(ub1.y));
    float a2 = xv.z + w0 * (bf2f(ua0.z) + bf2f(ub0.z)) + w1 * (bf2f(ua1.z) + bf2f(ub1.z));
    float a3 = xv.w + w0 * (bf2f(ua0.w) + bf2f(ub0.w)) + w1 * (bf2f(ua1.w) + bf2f(ub1.w));
    float s = a0 + a1 + a2 + a3;
    float q = a0 * a0 + a1 * a1 + a2 * a2 + a3 * a3;
    #pragma unroll
    for (int o = 32; o; o >>= 1) { s += __shfl_xor(s, o); q += __shfl_xor(q, o); }
    __shared__ float ls[4], lq[4];
    const int wav = tid >> 6, lane = tid & 63;
    if (lane == 0) { ls[wav] = s; lq[wav] = q; }
    __syncthreads();
    s = ls[0] + ls[1] + ls[2] + ls[3];
    q = lq[0] + lq[1] + lq[2] + lq[3];
    const float mu = s * (1.0f / 1024.0f);
    const float var = q * (1.0f / 1024.0f) - mu * mu;
    const float rs = rsqrtf(var + 1e-5f);
    const float4 g = *(const float4*)(gamma + j4);
    const float4 b = *(const float4*)(beta + j4);
    float4 o4;
    o4.x = (a0 - mu) * rs * g.x + b.x;
    o4.y = (a1 - mu) * rs * g.y + b.y;
    o4.z = (a2 - mu) * rs * g.z + b.z;
    o4.w = (a3 - mu) * rs * g.w + b.w;
    *(float4*)(out + (size_t)t * 1024 + j4) = o4;
}

extern "C" void kernel_launch(void* const* d_in, const int* in_sizes, int n_in,
                              void* d_out, int out_size, void* d_ws, size_t ws_size,
                              hipStream_t stream) {
    const float* x     = (const float*)d_in[0];   // [2,2048,1024]
    const float* rw    = (const float*)d_in[1];   // [8,1024]
    const float* rb    = (const float*)d_in[2];   // [8]
    const float* W1    = (const float*)d_in[3];   // [8,1024,4096]
    const float* b1    = (const float*)d_in[4];   // [8,4096]
    const float* W2    = (const float*)d_in[5];   // [8,4096,1024]
    const float* b2    = (const float*)d_in[6];   // [8,1024]
    const float* gamma = (const float*)d_in[7];   // [1024]
    const float* beta  = (const float*)d_in[8];   // [1024]
    float* out = (float*)d_out;

    // workspace carve (256B aligned)
    char* p = (char*)d_ws;
    auto alloc = [&](size_t bytes) { char* r = p; p += (bytes + 255) & ~(size_t)255; return r; };
    int*   counts  = (int*)alloc(16 * sizeof(int));      // counts[0..7], cursors[8..15]
    int*   cursors = counts + 8;
    int*   offsets = (int*)alloc(9 * sizeof(int));
    int*   eidx    = (int*)alloc(8192 * sizeof(int));
    float* wgt     = (float*)alloc(8192 * sizeof(float));
    int*   pos_of  = (int*)alloc(8192 * sizeof(int));
    int*   rows    = (int*)alloc(8192 * sizeof(int));
    u16*   xb      = (u16*)alloc((size_t)4096 * 1024 * 2);
    u16*   W1t     = (u16*)alloc((size_t)8 * 4096 * 1024 * 2);   // 64MB; dead after gemm1
    u16*   W2t     = (u16*)alloc((size_t)8 * 1024 * 4096 * 2);
    u16*   hbuf    = (u16*)alloc((size_t)8192 * 4096 * 2);
    // y0/y1 (bf16, 16MB each) alias W1t (dead after gemm1)
    u16* y0b = W1t;
    u16* y1b = W1t + (size_t)8192 * 1024;

    hipLaunchKernelGGL(k_init, dim3(1), dim3(64), 0, stream, counts);
    hipLaunchKernelGGL(k_router, dim3(1024), dim3(256), 0, stream, x, rw, rb, xb, eidx, wgt, counts);
    hipLaunchKernelGGL(k_offsets, dim3(1), dim3(64), 0, stream, counts, offsets);
    hipLaunchKernelGGL(k_place, dim3(32), dim3(256), 0, stream, eidx, offsets, cursors, rows, pos_of);
    // W1 [E][1024][4096] -> W1t [E][4096][1024]
    hipLaunchKernelGGL(k_transp, dim3(64, 16, 8), dim3(256), 0, stream, W1, W1t, 1024, 4096);
    // W2 [E][4096][1024] -> W2t [E][1024][4096]
    hipLaunchKernelGGL(k_transp, dim3(16, 64, 8), dim3(256), 0, stream, W2, W2t, 4096, 1024);
    hipLaunchKernelGGL(k_gemm1, dim3(8192), dim3(256), 0, stream, xb, W1t, b1, hbuf, rows, offsets);
    hipLaunchKernelGGL(k_gemm2, dim3(4096), dim3(256), 0, stream, hbuf, W2t, b2, y0b, y1b, offsets);
    hipLaunchKernelGGL(k_combine, dim3(4096), dim3(256), 0, stream, x, y0b, y1b, pos_of, wgt, gamma, beta, out);
}

// Round 9
// 442.652 us; speedup vs baseline: 1.0744x; 1.0239x over previous
//
#include <hip/hip_runtime.h>
#include <hip/hip_bf16.h>

// MoE head: router(top2 of 8) -> compact -> GEMM1+GELU -> GEMM2(split-K x4) -> combine+residual+LN
// R9: R8 core (2-deep dbuf, vmcnt(4), zero-conflict swizzle, setprio) +
//     gemm2 split-K 2->4 (active blocks 1024->2048, TLP for latency hiding) +
//     fused single-launch weight transpose.

typedef unsigned short u16;
typedef unsigned int u32;
typedef __attribute__((ext_vector_type(4))) float f32x4;
typedef __attribute__((ext_vector_type(8))) short s16x8;
typedef __attribute__((ext_vector_type(8))) unsigned short u16x8;

#define GLD16(gp, lp) __builtin_amdgcn_global_load_lds( \
    (const __attribute__((address_space(1))) void*)(gp), \
    (__attribute__((address_space(3))) void*)(lp), 16, 0, 0)

__device__ __forceinline__ u16 f2bf(float f) {
    union { float f; u32 u; } v; v.f = f;
    u32 u = v.u;
    return (u16)((u + 0x7fffu + ((u >> 16) & 1u)) >> 16);
}
__device__ __forceinline__ float bf2f(u16 h) {
    union { u32 u; float f; } v; v.u = ((u32)h) << 16; return v.f;
}

// fast GELU: v * sigmoid(1.59577v + 0.0713548v^3)
__device__ __forceinline__ float gelu_f(float v) {
    const float u = v * (0.7978845608f + 0.0356774081f * v * v);
    const float t = __expf(-2.0f * u);
    return v * __builtin_amdgcn_rcpf(1.0f + t);
}

// ---------------- K0: zero counts+cursors (16 ints) ----------------
__global__ void k_init(int* cc) { if (threadIdx.x < 16) cc[threadIdx.x] = 0; }

// ---------------- K1: router (fp32) + x->bf16 convert ----------------
__global__ __launch_bounds__(256) void k_router(
    const float* __restrict__ x, const float* __restrict__ rw, const float* __restrict__ rb,
    u16* __restrict__ xb, int* __restrict__ eidx, float* __restrict__ wgt, int* __restrict__ counts)
{
    const int wav = threadIdx.x >> 6, lane = threadIdx.x & 63;
    const int t = blockIdx.x * 4 + wav;
    const float* xt = x + (size_t)t * 1024;
    float acc[8] = {0.f,0.f,0.f,0.f,0.f,0.f,0.f,0.f};
    #pragma unroll
    for (int c = 0; c < 4; c++) {
        const int base = c * 256 + lane * 4;
        const float4 xv = *(const float4*)(xt + base);
        ushort4 pk;
        pk.x = f2bf(xv.x); pk.y = f2bf(xv.y); pk.z = f2bf(xv.z); pk.w = f2bf(xv.w);
        *(ushort4*)(xb + (size_t)t * 1024 + base) = pk;
        #pragma unroll
        for (int e = 0; e < 8; e++) {
            const float4 wv = *(const float4*)(rw + e * 1024 + base);
            acc[e] += xv.x * wv.x + xv.y * wv.y + xv.z * wv.z + xv.w * wv.w;
        }
    }
    #pragma unroll
    for (int e = 0; e < 8; e++) {
        #pragma unroll
        for (int s = 32; s; s >>= 1) acc[e] += __shfl_xor(acc[e], s);
    }
    if (lane == 0) {
        float v0 = -3e38f, v1 = -3e38f; int i0 = 0, i1 = 0;
        #pragma unroll
        for (int e = 0; e < 8; e++) {
            const float l = acc[e] + rb[e];
            if (l > v0) { v1 = v0; i1 = i0; v0 = l; i0 = e; }
            else if (l > v1) { v1 = l; i1 = e; }
        }
        const float w0 = 1.0f / (1.0f + expf(v1 - v0));
        eidx[2 * t] = i0; eidx[2 * t + 1] = i1;
        wgt[2 * t] = w0; wgt[2 * t + 1] = 1.0f - w0;
        atomicAdd(&counts[i0], 1); atomicAdd(&counts[i1], 1);
    }
}

// ---------------- K2: exclusive prefix of 8 counts ----------------
__global__ void k_offsets(const int* __restrict__ counts, int* __restrict__ offsets) {
    if (threadIdx.x == 0) {
        int s = 0;
        for (int e = 0; e < 8; e++) { offsets[e] = s; s += counts[e]; }
        offsets[8] = s;
    }
}

// ---------------- K3: place assignments into compacted row list ----------------
__global__ __launch_bounds__(256) void k_place(
    const int* __restrict__ eidx, const int* __restrict__ offsets, int* __restrict__ cursors,
    int* __restrict__ rows, int* __restrict__ pos_of)
{
    const int a = blockIdx.x * 256 + threadIdx.x;   // 8192 assignments
    const int e = eidx[a];
    const int pos = offsets[e] + atomicAdd(&cursors[e], 1);
    rows[pos] = a >> 1;
    pos_of[a] = pos;
}

// ---------------- K4: fused LDS-tiled transpose + fp32->bf16 (W1 and W2, one launch) ----------------
// 1D grid 16384: id<8192 -> W1 [8][1024][4096] tiles (64x16 per e); else W2 [8][4096][1024] (16x64 per e).
__device__ __forceinline__ void transp_tile(
    const float* __restrict__ s, u16* __restrict__ d, int R, int C, int c0, int r0, int tid)
{
    __shared__ float tl[64][66];   // [col][row]
    const int rrow = tid >> 4, rc4 = (tid & 15) * 4;
    #pragma unroll
    for (int j = 0; j < 4; j++) {
        const float4 v = *(const float4*)(s + (size_t)(r0 + rrow + j * 16) * C + c0 + rc4);
        tl[rc4 + 0][rrow + j * 16] = v.x;
        tl[rc4 + 1][rrow + j * 16] = v.y;
        tl[rc4 + 2][rrow + j * 16] = v.z;
        tl[rc4 + 3][rrow + j * 16] = v.w;
    }
    __syncthreads();
    const int wcol = tid >> 3, wr8 = (tid & 7) * 8;
    #pragma unroll
    for (int j = 0; j < 2; j++) {
        const int cc = wcol + j * 32;
        u16x8 o;
        #pragma unroll
        for (int k = 0; k < 4; k++) {
            const float2 f = *(const float2*)(&tl[cc][wr8 + k * 2]);
            o[k * 2] = f2bf(f.x);
            o[k * 2 + 1] = f2bf(f.y);
        }
        *(u16x8*)(d + (size_t)(c0 + cc) * R + r0 + wr8) = o;
    }
}

__global__ __launch_bounds__(256) void k_transp_fused(
    const float* __restrict__ W1, u16* __restrict__ W1t,
    const float* __restrict__ W2, u16* __restrict__ W2t)
{
    const int id = blockIdx.x;
    const int tid = threadIdx.x;
    if (id < 8192) {
        // W1: R=1024, C=4096; per-e tiles 64x16 (cx 0..63, ry 0..15)
        const int e = id >> 10, rem = id & 1023;
        const int cx = rem & 63, ry = rem >> 6;
        transp_tile(W1 + (size_t)e * 1024 * 4096, W1t + (size_t)e * 1024 * 4096,
                    1024, 4096, cx * 64, ry * 64, tid);
    } else {
        // W2: R=4096, C=1024; per-e tiles 16x64 (cx 0..15, ry 0..63)
        const int id2 = id - 8192;
        const int e = id2 >> 10, rem = id2 & 1023;
        const int cx = rem & 15, ry = rem >> 4;
        transp_tile(W2 + (size_t)e * 4096 * 1024, W2t + (size_t)e * 4096 * 1024,
                    4096, 1024, cx * 64, ry * 64, tid);
    }
}

// shared GEMM macros: LDS [2][128][32] bf16 per operand, linear dest;
// source column pre-swizzled (chunk ^= (row>>1)&3), read offset swizzled to match.
#define STAGE_T(b, k0) { \
    char* ad = (char*)At + (b) * 8192 + wav * 1024; \
    char* bd = (char*)Bt + (b) * 8192 + wav * 1024; \
    GLD16(a_src0 + (k0), ad); \
    GLD16(a_src1 + (k0), ad + 4096); \
    GLD16(b_src0 + (k0), bd); \
    GLD16(b_src1 + (k0), bd + 4096); }

#define COMPUTE_T(b) { \
    const u16* Abp = Ab + (b) * 4096; \
    const u16* Bbp = Bb + (b) * 4096; \
    s16x8 af[4], bfr[4]; \
    _Pragma("unroll") \
    for (int i = 0; i < 4; i++) { \
        af[i]  = *(const s16x8*)(Abp + i * 512); \
        bfr[i] = *(const s16x8*)(Bbp + i * 512); \
    } \
    __builtin_amdgcn_s_setprio(1); \
    _Pragma("unroll") \
    for (int mi = 0; mi < 4; mi++) \
        _Pragma("unroll") \
        for (int ni = 0; ni < 4; ni++) \
            acc[mi][ni] = __builtin_amdgcn_mfma_f32_16x16x32_bf16(af[mi], bfr[ni], acc[mi][ni], 0, 0, 0); \
    __builtin_amdgcn_s_setprio(0); }

#define VMCNT4 asm volatile("s_waitcnt vmcnt(4)" ::: "memory")
#define VMCNT0 asm volatile("s_waitcnt vmcnt(0)" ::: "memory")
#define BAR __builtin_amdgcn_s_barrier()

// ---------------- K5: grouped GEMM1 + bias + fast GELU -> h (bf16) ----------------
// 8192 blocks flat; swz -> (e, x=n-tile of 32, y=row-tile of 32, y fastest)
__global__ __launch_bounds__(256, 4) void k_gemm1(
    const u16* __restrict__ xb, const u16* __restrict__ W1t, const float* __restrict__ b1,
    u16* __restrict__ hbuf, const int* __restrict__ rows, const int* __restrict__ offsets)
{
    const int fid = blockIdx.x;
    const int swz = (fid & 7) * 1024 + (fid >> 3);   // bijective, nwg=8192
    const int y = swz & 31, xx = (swz >> 5) & 31, e = swz >> 10;

    const int off = offsets[e], cnt = offsets[e + 1] - off;
    const int row0 = y * 128;
    if (row0 >= cnt) return;
    const int n0 = xx * 128;
    const int tid = threadIdx.x;
    const int lane = tid & 63, wav = tid >> 6, lane15 = lane & 15;

    __shared__ u16 At[2][128][32];
    __shared__ u16 Bt[2][128][32];

    const int ar0 = tid >> 2;
    const int cl8 = (((tid & 3) ^ ((tid >> 3) & 3))) * 8;   // swizzled source chunk
    const int t0 = rows[off + min(row0 + ar0, cnt - 1)];
    const int t1 = rows[off + min(row0 + ar0 + 64, cnt - 1)];
    const u16* a_src0 = xb + (size_t)t0 * 1024 + cl8;
    const u16* a_src1 = xb + (size_t)t1 * 1024 + cl8;
    const u16* b_src0 = W1t + ((size_t)e * 4096 + n0 + ar0) * 1024 + cl8;
    const u16* b_src1 = b_src0 + (size_t)64 * 1024;

    f32x4 acc[4][4] = {};
    const int wr = wav >> 1, wc = wav & 1;
    const int koff = ((lane >> 4) ^ ((lane >> 1) & 3)) * 8;  // swizzled read chunk
    const u16* Ab = &At[0][wr * 64 + lane15][koff];
    const u16* Bb = &Bt[0][wc * 64 + lane15][koff];

    STAGE_T(0, 0);
    int b = 0;
    for (int k0 = 32; k0 < 1024; k0 += 32) {
        STAGE_T(b ^ 1, k0);
        VMCNT4;             // current buffer's 4 loads landed (next 4 stay in flight)
        BAR;
        COMPUTE_T(b);
        BAR;                // all waves done reading buffer b
        b ^= 1;
    }
    VMCNT0;
    BAR;
    COMPUTE_T(b);

    const int rb4 = (lane >> 4) * 4;
    const int colbase = n0 + wc * 64 + lane15;
    float bias[4];
    #pragma unroll
    for (int ni = 0; ni < 4; ni++) bias[ni] = b1[e * 4096 + colbase + ni * 16];
    #pragma unroll
    for (int mi = 0; mi < 4; mi++) {
        #pragma unroll
        for (int j = 0; j < 4; j++) {
            const int lrow = wr * 64 + mi * 16 + rb4 + j;
            if (row0 + lrow < cnt) {
                const size_t gr = (size_t)(off + row0 + lrow);
                #pragma unroll
                for (int ni = 0; ni < 4; ni++) {
                    const float v = acc[mi][ni][j] + bias[ni];
                    hbuf[gr * 4096 + colbase + ni * 16] = f2bf(gelu_f(v));
                }
            }
        }
    }
}

// ---------------- K6: grouped GEMM2 (split-K x4) + bias -> yb[4] (bf16) ----------------
// 8192 blocks flat; swz -> (z = e*4+kq, x=n-tile of 8, y=row-tile of 32, y fastest)
__global__ __launch_bounds__(256, 4) void k_gemm2(
    const u16* __restrict__ hbuf, const u16* __restrict__ W2t, const float* __restrict__ b2,
    u16* __restrict__ yb, const int* __restrict__ offsets)
{
    const int fid = blockIdx.x;
    const int swz = (fid & 7) * 1024 + (fid >> 3);   // bijective, nwg=8192
    const int y = swz & 31, xx = (swz >> 5) & 7, z = swz >> 8;
    const int e = z >> 2, kq = z & 3;

    const int off = offsets[e], cnt = offsets[e + 1] - off;
    const int row0 = y * 128;
    if (row0 >= cnt) return;
    const int n0 = xx * 128;
    const int tid = threadIdx.x;
    const int lane = tid & 63, wav = tid >> 6, lane15 = lane & 15;
    const int kbase = kq * 1024;

    __shared__ u16 At[2][128][32];
    __shared__ u16 Bt[2][128][32];

    const int ar0 = tid >> 2;
    const int cl8 = (((tid & 3) ^ ((tid >> 3) & 3))) * 8;
    const u16* a_src0 = hbuf + (size_t)(off + min(row0 + ar0, cnt - 1)) * 4096 + kbase + cl8;
    const u16* a_src1 = hbuf + (size_t)(off + min(row0 + ar0 + 64, cnt - 1)) * 4096 + kbase + cl8;
    const u16* b_src0 = W2t + ((size_t)e * 1024 + n0 + ar0) * 4096 + kbase + cl8;
    const u16* b_src1 = b_src0 + (size_t)64 * 4096;

    f32x4 acc[4][4] = {};
    const int wr = wav >> 1, wc = wav & 1;
    const int koff = ((lane >> 4) ^ ((lane >> 1) & 3)) * 8;
    const u16* Ab = &At[0][wr * 64 + lane15][koff];
    const u16* Bb = &Bt[0][wc * 64 + lane15][koff];

    STAGE_T(0, 0);
    int b = 0;
    for (int k0 = 32; k0 < 1024; k0 += 32) {
        STAGE_T(b ^ 1, k0);
        VMCNT4;
        BAR;
        COMPUTE_T(b);
        BAR;
        b ^= 1;
    }
    VMCNT0;
    BAR;
    COMPUTE_T(b);

    u16* yy = yb + (size_t)kq * 8192 * 1024;
    const int rb4 = (lane >> 4) * 4;
    const int colbase = n0 + wc * 64 + lane15;
    float bias[4];
    #pragma unroll
    for (int ni = 0; ni < 4; ni++) bias[ni] = (kq == 0) ? b2[e * 1024 + colbase + ni * 16] : 0.f;
    #pragma unroll
    for (int mi = 0; mi < 4; mi++) {
        #pragma unroll
        for (int j = 0; j < 4; j++) {
            const int lrow = wr * 64 + mi * 16 + rb4 + j;
            if (row0 + lrow < cnt) {
                const size_t gr = (size_t)(off + row0 + lrow);
                #pragma unroll
                for (int ni = 0; ni < 4; ni++)
                    yy[gr * 1024 + colbase + ni * 16] = f2bf(acc[mi][ni][j] + bias[ni]);
            }
        }
    }
}

// ---------------- K7: combine (w0*sum4(y[p0]) + w1*sum4(y[p1]) + residual) + LayerNorm ----------------
__global__ __launch_bounds__(256) void k_combine(
    const float* __restrict__ x, const u16* __restrict__ yb,
    const int* __restrict__ pos_of, const float* __restrict__ wgt,
    const float* __restrict__ gamma, const float* __restrict__ beta,
    float* __restrict__ out)
{
    const int t = blockIdx.x;
    const int tid = threadIdx.x;
    const int p0 = pos_of[2 * t], p1 = pos_of[2 * t + 1];
    const float w0 = wgt[2 * t], w1 = wgt[2 * t + 1];
    const int j4 = tid * 4;
    const float4 xv = *(const float4*)(x + (size_t)t * 1024 + j4);
    float s0[4] = {0.f, 0.f, 0.f, 0.f};
    float s1[4] = {0.f, 0.f, 0.f, 0.f};
    #pragma unroll
    for (int kq = 0; kq < 4; kq++) {
        const u16* ybq = yb + (size_t)kq * 8192 * 1024;
        const ushort4 u0 = *(const ushort4*)(ybq + (size_t)p0 * 1024 + j4);
        const ushort4 u1 = *(const ushort4*)(ybq + (size_t)p1 * 1024 + j4);
        s0[0] += bf2f(u0.x); s0[1] += bf2f(u0.y); s0[2] += bf2f(u0.z); s0[3] += bf2f(u0.w);
        s1[0] += bf2f(u1.x); s1[1] += bf2f(u1.y); s1[2] += bf2f(u1.z); s1[3] += bf2f(u1.w);
    }
    float a0 = xv.x + w0 * s0[0] + w1 * s1[0];
    float a1 = xv.y + w0 * s0[1] + w1 * s1[1];
    float a2 = xv.z + w0 * s0[2] + w1 * s1[2];
    float a3 = xv.w + w0 * s0[3] + w1 * s1[3];
    float s = a0 + a1 + a2 + a3;
    float q = a0 * a0 + a1 * a1 + a2 * a2 + a3 * a3;
    #pragma unroll
    for (int o = 32; o; o >>= 1) { s += __shfl_xor(s, o); q += __shfl_xor(q, o); }
    __shared__ float ls[4], lq[4];
    const int wav = tid >> 6, lane = tid & 63;
    if (lane == 0) { ls[wav] = s; lq[wav] = q; }
    __syncthreads();
    s = ls[0] + ls[1] + ls[2] + ls[3];
    q = lq[0] + lq[1] + lq[2] + lq[3];
    const float mu = s * (1.0f / 1024.0f);
    const float var = q * (1.0f / 1024.0f) - mu * mu;
    const float rs = rsqrtf(var + 1e-5f);
    const float4 g = *(const float4*)(gamma + j4);
    const float4 b = *(const float4*)(beta + j4);
    float4 o4;
    o4.x = (a0 - mu) * rs * g.x + b.x;
    o4.y = (a1 - mu) * rs * g.y + b.y;
    o4.z = (a2 - mu) * rs * g.z + b.z;
    o4.w = (a3 - mu) * rs * g.w + b.w;
    *(float4*)(out + (size_t)t * 1024 + j4) = o4;
}

extern "C" void kernel_launch(void* const* d_in, const int* in_sizes, int n_in,
                              void* d_out, int out_size, void* d_ws, size_t ws_size,
                              hipStream_t stream) {
    const float* x     = (const float*)d_in[0];   // [2,2048,1024]
    const float* rw    = (const float*)d_in[1];   // [8,1024]
    const float* rb    = (const float*)d_in[2];   // [8]
    const float* W1    = (const float*)d_in[3];   // [8,1024,4096]
    const float* b1    = (const float*)d_in[4];   // [8,4096]
    const float* W2    = (const float*)d_in[5];   // [8,4096,1024]
    const float* b2    = (const float*)d_in[6];   // [8,1024]
    const float* gamma = (const float*)d_in[7];   // [1024]
    const float* beta  = (const float*)d_in[8];   // [1024]
    float* out = (float*)d_out;

    // workspace carve (256B aligned)
    char* p = (char*)d_ws;
    auto alloc = [&](size_t bytes) { char* r = p; p += (bytes + 255) & ~(size_t)255; return r; };
    int*   counts  = (int*)alloc(16 * sizeof(int));      // counts[0..7], cursors[8..15]
    int*   cursors = counts + 8;
    int*   offsets = (int*)alloc(9 * sizeof(int));
    int*   eidx    = (int*)alloc(8192 * sizeof(int));
    float* wgt     = (float*)alloc(8192 * sizeof(float));
    int*   pos_of  = (int*)alloc(8192 * sizeof(int));
    int*   rows    = (int*)alloc(8192 * sizeof(int));
    u16*   xb      = (u16*)alloc((size_t)4096 * 1024 * 2);
    u16*   W1t     = (u16*)alloc((size_t)8 * 4096 * 1024 * 2);   // 64MB; dead after gemm1
    u16*   W2t     = (u16*)alloc((size_t)8 * 1024 * 4096 * 2);
    u16*   hbuf    = (u16*)alloc((size_t)8192 * 4096 * 2);
    // yb = 4 bf16 partial buffers (4 x 16MB = 64MB) alias W1t (dead after gemm1)
    u16* yb = W1t;

    hipLaunchKernelGGL(k_init, dim3(1), dim3(64), 0, stream, counts);
    hipLaunchKernelGGL(k_router, dim3(1024), dim3(256), 0, stream, x, rw, rb, xb, eidx, wgt, counts);
    hipLaunchKernelGGL(k_offsets, dim3(1), dim3(64), 0, stream, counts, offsets);
    hipLaunchKernelGGL(k_place, dim3(32), dim3(256), 0, stream, eidx, offsets, cursors, rows, pos_of);
    hipLaunchKernelGGL(k_transp_fused, dim3(16384), dim3(256), 0, stream, W1, W1t, W2, W2t);
    hipLaunchKernelGGL(k_gemm1, dim3(8192), dim3(256), 0, stream, xb, W1t, b1, hbuf, rows, offsets);
    hipLaunchKernelGGL(k_gemm2, dim3(8192), dim3(256), 0, stream, hbuf, W2t, b2, yb, offsets);
    hipLaunchKernelGGL(k_combine, dim3(4096), dim3(256), 0, stream, x, yb, pos_of, wgt, gamma, beta, out);
}

// Round 10
// 431.425 us; speedup vs baseline: 1.1024x; 1.0260x over previous
//
#include <hip/hip_runtime.h>
#include <hip/hip_bf16.h>

// MoE head: router(top2 of 8) -> compact -> GEMM1+GELU -> GEMM2(split-K x4) -> combine+residual+LN
// R10: launch-graph consolidation. Router fused into the transpose launch (concurrent,
//      router hides under BW-bound transpose); offsets folded into place. 6 launches total.
//      GEMMs byte-identical to R9 (2-deep dbuf, vmcnt(4), zero-conflict swizzle, setprio).

typedef unsigned short u16;
typedef unsigned int u32;
typedef __attribute__((ext_vector_type(4))) float f32x4;
typedef __attribute__((ext_vector_type(8))) short s16x8;
typedef __attribute__((ext_vector_type(8))) unsigned short u16x8;

#define GLD16(gp, lp) __builtin_amdgcn_global_load_lds( \
    (const __attribute__((address_space(1))) void*)(gp), \
    (__attribute__((address_space(3))) void*)(lp), 16, 0, 0)

__device__ __forceinline__ u16 f2bf(float f) {
    union { float f; u32 u; } v; v.f = f;
    u32 u = v.u;
    return (u16)((u + 0x7fffu + ((u >> 16) & 1u)) >> 16);
}
__device__ __forceinline__ float bf2f(u16 h) {
    union { u32 u; float f; } v; v.u = ((u32)h) << 16; return v.f;
}

// fast GELU: v * sigmoid(1.59577v + 0.0713548v^3)
__device__ __forceinline__ float gelu_f(float v) {
    const float u = v * (0.7978845608f + 0.0356774081f * v * v);
    const float t = __expf(-2.0f * u);
    return v * __builtin_amdgcn_rcpf(1.0f + t);
}

// ---------------- K0: zero counts+cursors (16 ints) ----------------
__global__ void k_init(int* cc) { if (threadIdx.x < 16) cc[threadIdx.x] = 0; }

// ---------------- transpose tile helper (LDS-tiled, coalesced both sides) ----------------
__device__ __forceinline__ void transp_tile(
    const float* __restrict__ s, u16* __restrict__ d, int R, int C, int c0, int r0, int tid)
{
    __shared__ float tl[64][66];   // [col][row]
    const int rrow = tid >> 4, rc4 = (tid & 15) * 4;
    #pragma unroll
    for (int j = 0; j < 4; j++) {
        const float4 v = *(const float4*)(s + (size_t)(r0 + rrow + j * 16) * C + c0 + rc4);
        tl[rc4 + 0][rrow + j * 16] = v.x;
        tl[rc4 + 1][rrow + j * 16] = v.y;
        tl[rc4 + 2][rrow + j * 16] = v.z;
        tl[rc4 + 3][rrow + j * 16] = v.w;
    }
    __syncthreads();
    const int wcol = tid >> 3, wr8 = (tid & 7) * 8;
    #pragma unroll
    for (int j = 0; j < 2; j++) {
        const int cc = wcol + j * 32;
        u16x8 o;
        #pragma unroll
        for (int k = 0; k < 4; k++) {
            const float2 f = *(const float2*)(&tl[cc][wr8 + k * 2]);
            o[k * 2] = f2bf(f.x);
            o[k * 2 + 1] = f2bf(f.y);
        }
        *(u16x8*)(d + (size_t)(c0 + cc) * R + r0 + wr8) = o;
    }
}

// ---------------- K1: fused router + weight transpose (17408 blocks) ----------------
// blocks 0..1023: router (4 tokens each) + x->bf16; blocks 1024..9215: W1 tiles;
// blocks 9216..17407: W2 tiles.
__global__ __launch_bounds__(256) void k_pre(
    const float* __restrict__ x, const float* __restrict__ rw, const float* __restrict__ rb,
    u16* __restrict__ xb, int* __restrict__ eidx, float* __restrict__ wgt, int* __restrict__ counts,
    const float* __restrict__ W1, u16* __restrict__ W1t,
    const float* __restrict__ W2, u16* __restrict__ W2t)
{
    const int id = blockIdx.x;
    const int tid = threadIdx.x;
    if (id >= 1024) {
        const int id2 = id - 1024;
        if (id2 < 8192) {
            // W1: R=1024, C=4096; per-e tiles 64x16 (cx 0..63, ry 0..15)
            const int e = id2 >> 10, rem = id2 & 1023;
            const int cx = rem & 63, ry = rem >> 6;
            transp_tile(W1 + (size_t)e * 1024 * 4096, W1t + (size_t)e * 1024 * 4096,
                        1024, 4096, cx * 64, ry * 64, tid);
        } else {
            // W2: R=4096, C=1024; per-e tiles 16x64 (cx 0..15, ry 0..63)
            const int id3 = id2 - 8192;
            const int e = id3 >> 10, rem = id3 & 1023;
            const int cx = rem & 15, ry = rem >> 4;
            transp_tile(W2 + (size_t)e * 4096 * 1024, W2t + (size_t)e * 4096 * 1024,
                        4096, 1024, cx * 64, ry * 64, tid);
        }
        return;
    }
    // router path
    const int wav = tid >> 6, lane = tid & 63;
    const int t = id * 4 + wav;
    const float* xt = x + (size_t)t * 1024;
    float acc[8] = {0.f,0.f,0.f,0.f,0.f,0.f,0.f,0.f};
    #pragma unroll
    for (int c = 0; c < 4; c++) {
        const int base = c * 256 + lane * 4;
        const float4 xv = *(const float4*)(xt + base);
        ushort4 pk;
        pk.x = f2bf(xv.x); pk.y = f2bf(xv.y); pk.z = f2bf(xv.z); pk.w = f2bf(xv.w);
        *(ushort4*)(xb + (size_t)t * 1024 + base) = pk;
        #pragma unroll
        for (int e = 0; e < 8; e++) {
            const float4 wv = *(const float4*)(rw + e * 1024 + base);
            acc[e] += xv.x * wv.x + xv.y * wv.y + xv.z * wv.z + xv.w * wv.w;
        }
    }
    #pragma unroll
    for (int e = 0; e < 8; e++) {
        #pragma unroll
        for (int s = 32; s; s >>= 1) acc[e] += __shfl_xor(acc[e], s);
    }
    if (lane == 0) {
        float v0 = -3e38f, v1 = -3e38f; int i0 = 0, i1 = 0;
        #pragma unroll
        for (int e = 0; e < 8; e++) {
            const float l = acc[e] + rb[e];
            if (l > v0) { v1 = v0; i1 = i0; v0 = l; i0 = e; }
            else if (l > v1) { v1 = l; i1 = e; }
        }
        const float w0 = 1.0f / (1.0f + expf(v1 - v0));
        eidx[2 * t] = i0; eidx[2 * t + 1] = i1;
        wgt[2 * t] = w0; wgt[2 * t + 1] = 1.0f - w0;
        atomicAdd(&counts[i0], 1); atomicAdd(&counts[i1], 1);
    }
}

// ---------------- K2: place (prefix computed locally from counts; block 0 publishes offsets) ----------------
__global__ __launch_bounds__(256) void k_place2(
    const int* __restrict__ eidx, const int* __restrict__ counts, int* __restrict__ cursors,
    int* __restrict__ offsets, int* __restrict__ rows, int* __restrict__ pos_of)
{
    int base[8];
    int s = 0;
    #pragma unroll
    for (int e = 0; e < 8; e++) { base[e] = s; s += counts[e]; }
    if (blockIdx.x == 0 && threadIdx.x == 0) {
        #pragma unroll
        for (int e = 0; e < 8; e++) offsets[e] = base[e];
        offsets[8] = s;
    }
    const int a = blockIdx.x * 256 + threadIdx.x;   // 8192 assignments
    const int e = eidx[a];
    const int pos = base[e] + atomicAdd(&cursors[e], 1);
    rows[pos] = a >> 1;
    pos_of[a] = pos;
}

// shared GEMM macros: LDS [2][128][32] bf16 per operand, linear dest;
// source column pre-swizzled (chunk ^= (row>>1)&3), read offset swizzled to match.
#define STAGE_T(b, k0) { \
    char* ad = (char*)At + (b) * 8192 + wav * 1024; \
    char* bd = (char*)Bt + (b) * 8192 + wav * 1024; \
    GLD16(a_src0 + (k0), ad); \
    GLD16(a_src1 + (k0), ad + 4096); \
    GLD16(b_src0 + (k0), bd); \
    GLD16(b_src1 + (k0), bd + 4096); }

#define COMPUTE_T(b) { \
    const u16* Abp = Ab + (b) * 4096; \
    const u16* Bbp = Bb + (b) * 4096; \
    s16x8 af[4], bfr[4]; \
    _Pragma("unroll") \
    for (int i = 0; i < 4; i++) { \
        af[i]  = *(const s16x8*)(Abp + i * 512); \
        bfr[i] = *(const s16x8*)(Bbp + i * 512); \
    } \
    __builtin_amdgcn_s_setprio(1); \
    _Pragma("unroll") \
    for (int mi = 0; mi < 4; mi++) \
        _Pragma("unroll") \
        for (int ni = 0; ni < 4; ni++) \
            acc[mi][ni] = __builtin_amdgcn_mfma_f32_16x16x32_bf16(af[mi], bfr[ni], acc[mi][ni], 0, 0, 0); \
    __builtin_amdgcn_s_setprio(0); }

#define VMCNT4 asm volatile("s_waitcnt vmcnt(4)" ::: "memory")
#define VMCNT0 asm volatile("s_waitcnt vmcnt(0)" ::: "memory")
#define BAR __builtin_amdgcn_s_barrier()

// ---------------- K5: grouped GEMM1 + bias + fast GELU -> h (bf16) ----------------
// 8192 blocks flat; swz -> (e, x=n-tile of 32, y=row-tile of 32, y fastest)
__global__ __launch_bounds__(256, 4) void k_gemm1(
    const u16* __restrict__ xb, const u16* __restrict__ W1t, const float* __restrict__ b1,
    u16* __restrict__ hbuf, const int* __restrict__ rows, const int* __restrict__ offsets)
{
    const int fid = blockIdx.x;
    const int swz = (fid & 7) * 1024 + (fid >> 3);   // bijective, nwg=8192
    const int y = swz & 31, xx = (swz >> 5) & 31, e = swz >> 10;

    const int off = offsets[e], cnt = offsets[e + 1] - off;
    const int row0 = y * 128;
    if (row0 >= cnt) return;
    const int n0 = xx * 128;
    const int tid = threadIdx.x;
    const int lane = tid & 63, wav = tid >> 6, lane15 = lane & 15;

    __shared__ u16 At[2][128][32];
    __shared__ u16 Bt[2][128][32];

    const int ar0 = tid >> 2;
    const int cl8 = (((tid & 3) ^ ((tid >> 3) & 3))) * 8;   // swizzled source chunk
    const int t0 = rows[off + min(row0 + ar0, cnt - 1)];
    const int t1 = rows[off + min(row0 + ar0 + 64, cnt - 1)];
    const u16* a_src0 = xb + (size_t)t0 * 1024 + cl8;
    const u16* a_src1 = xb + (size_t)t1 * 1024 + cl8;
    const u16* b_src0 = W1t + ((size_t)e * 4096 + n0 + ar0) * 1024 + cl8;
    const u16* b_src1 = b_src0 + (size_t)64 * 1024;

    f32x4 acc[4][4] = {};
    const int wr = wav >> 1, wc = wav & 1;
    const int koff = ((lane >> 4) ^ ((lane >> 1) & 3)) * 8;  // swizzled read chunk
    const u16* Ab = &At[0][wr * 64 + lane15][koff];
    const u16* Bb = &Bt[0][wc * 64 + lane15][koff];

    STAGE_T(0, 0);
    int b = 0;
    for (int k0 = 32; k0 < 1024; k0 += 32) {
        STAGE_T(b ^ 1, k0);
        VMCNT4;             // current buffer's 4 loads landed (next 4 stay in flight)
        BAR;
        COMPUTE_T(b);
        BAR;                // all waves done reading buffer b
        b ^= 1;
    }
    VMCNT0;
    BAR;
    COMPUTE_T(b);

    const int rb4 = (lane >> 4) * 4;
    const int colbase = n0 + wc * 64 + lane15;
    float bias[4];
    #pragma unroll
    for (int ni = 0; ni < 4; ni++) bias[ni] = b1[e * 4096 + colbase + ni * 16];
    #pragma unroll
    for (int mi = 0; mi < 4; mi++) {
        #pragma unroll
        for (int j = 0; j < 4; j++) {
            const int lrow = wr * 64 + mi * 16 + rb4 + j;
            if (row0 + lrow < cnt) {
                const size_t gr = (size_t)(off + row0 + lrow);
                #pragma unroll
                for (int ni = 0; ni < 4; ni++) {
                    const float v = acc[mi][ni][j] + bias[ni];
                    hbuf[gr * 4096 + colbase + ni * 16] = f2bf(gelu_f(v));
                }
            }
        }
    }
}

// ---------------- K6: grouped GEMM2 (split-K x4) + bias -> yb[4] (bf16) ----------------
// 8192 blocks flat; swz -> (z = e*4+kq, x=n-tile of 8, y=row-tile of 32, y fastest)
__global__ __launch_bounds__(256, 4) void k_gemm2(
    const u16* __restrict__ hbuf, const u16* __restrict__ W2t, const float* __restrict__ b2,
    u16* __restrict__ yb, const int* __restrict__ offsets)
{
    const int fid = blockIdx.x;
    const int swz = (fid & 7) * 1024 + (fid >> 3);   // bijective, nwg=8192
    const int y = swz & 31, xx = (swz >> 5) & 7, z = swz >> 8;
    const int e = z >> 2, kq = z & 3;

    const int off = offsets[e], cnt = offsets[e + 1] - off;
    const int row0 = y * 128;
    if (row0 >= cnt) return;
    const int n0 = xx * 128;
    const int tid = threadIdx.x;
    const int lane = tid & 63, wav = tid >> 6, lane15 = lane & 15;
    const int kbase = kq * 1024;

    __shared__ u16 At[2][128][32];
    __shared__ u16 Bt[2][128][32];

    const int ar0 = tid >> 2;
    const int cl8 = (((tid & 3) ^ ((tid >> 3) & 3))) * 8;
    const u16* a_src0 = hbuf + (size_t)(off + min(row0 + ar0, cnt - 1)) * 4096 + kbase + cl8;
    const u16* a_src1 = hbuf + (size_t)(off + min(row0 + ar0 + 64, cnt - 1)) * 4096 + kbase + cl8;
    const u16* b_src0 = W2t + ((size_t)e * 1024 + n0 + ar0) * 4096 + kbase + cl8;
    const u16* b_src1 = b_src0 + (size_t)64 * 4096;

    f32x4 acc[4][4] = {};
    const int wr = wav >> 1, wc = wav & 1;
    const int koff = ((lane >> 4) ^ ((lane >> 1) & 3)) * 8;
    const u16* Ab = &At[0][wr * 64 + lane15][koff];
    const u16* Bb = &Bt[0][wc * 64 + lane15][koff];

    STAGE_T(0, 0);
    int b = 0;
    for (int k0 = 32; k0 < 1024; k0 += 32) {
        STAGE_T(b ^ 1, k0);
        VMCNT4;
        BAR;
        COMPUTE_T(b);
        BAR;
        b ^= 1;
    }
    VMCNT0;
    BAR;
    COMPUTE_T(b);

    u16* yy = yb + (size_t)kq * 8192 * 1024;
    const int rb4 = (lane >> 4) * 4;
    const int colbase = n0 + wc * 64 + lane15;
    float bias[4];
    #pragma unroll
    for (int ni = 0; ni < 4; ni++) bias[ni] = (kq == 0) ? b2[e * 1024 + colbase + ni * 16] : 0.f;
    #pragma unroll
    for (int mi = 0; mi < 4; mi++) {
        #pragma unroll
        for (int j = 0; j < 4; j++) {
            const int lrow = wr * 64 + mi * 16 + rb4 + j;
            if (row0 + lrow < cnt) {
                const size_t gr = (size_t)(off + row0 + lrow);
                #pragma unroll
                for (int ni = 0; ni < 4; ni++)
                    yy[gr * 1024 + colbase + ni * 16] = f2bf(acc[mi][ni][j] + bias[ni]);
            }
        }
    }
}

// ---------------- K7: combine (w0*sum4(y[p0]) + w1*sum4(y[p1]) + residual) + LayerNorm ----------------
__global__ __launch_bounds__(256) void k_combine(
    const float* __restrict__ x, const u16* __restrict__ yb,
    const int* __restrict__ pos_of, const float* __restrict__ wgt,
    const float* __restrict__ gamma, const float* __restrict__ beta,
    float* __restrict__ out)
{
    const int t = blockIdx.x;
    const int tid = threadIdx.x;
    const int p0 = pos_of[2 * t], p1 = pos_of[2 * t + 1];
    const float w0 = wgt[2 * t], w1 = wgt[2 * t + 1];
    const int j4 = tid * 4;
    const float4 xv = *(const float4*)(x + (size_t)t * 1024 + j4);
    float s0[4] = {0.f, 0.f, 0.f, 0.f};
    float s1[4] = {0.f, 0.f, 0.f, 0.f};
    #pragma unroll
    for (int kq = 0; kq < 4; kq++) {
        const u16* ybq = yb + (size_t)kq * 8192 * 1024;
        const ushort4 u0 = *(const ushort4*)(ybq + (size_t)p0 * 1024 + j4);
        const ushort4 u1 = *(const ushort4*)(ybq + (size_t)p1 * 1024 + j4);
        s0[0] += bf2f(u0.x); s0[1] += bf2f(u0.y); s0[2] += bf2f(u0.z); s0[3] += bf2f(u0.w);
        s1[0] += bf2f(u1.x); s1[1] += bf2f(u1.y); s1[2] += bf2f(u1.z); s1[3] += bf2f(u1.w);
    }
    float a0 = xv.x + w0 * s0[0] + w1 * s1[0];
    float a1 = xv.y + w0 * s0[1] + w1 * s1[1];
    float a2 = xv.z + w0 * s0[2] + w1 * s1[2];
    float a3 = xv.w + w0 * s0[3] + w1 * s1[3];
    float s = a0 + a1 + a2 + a3;
    float q = a0 * a0 + a1 * a1 + a2 * a2 + a3 * a3;
    #pragma unroll
    for (int o = 32; o; o >>= 1) { s += __shfl_xor(s, o); q += __shfl_xor(q, o); }
    __shared__ float ls[4], lq[4];
    const int wav = tid >> 6, lane = tid & 63;
    if (lane == 0) { ls[wav] = s; lq[wav] = q; }
    __syncthreads();
    s = ls[0] + ls[1] + ls[2] + ls[3];
    q = lq[0] + lq[1] + lq[2] + lq[3];
    const float mu = s * (1.0f / 1024.0f);
    const float var = q * (1.0f / 1024.0f) - mu * mu;
    const float rs = rsqrtf(var + 1e-5f);
    const float4 g = *(const float4*)(gamma + j4);
    const float4 b = *(const float4*)(beta + j4);
    float4 o4;
    o4.x = (a0 - mu) * rs * g.x + b.x;
    o4.y = (a1 - mu) * rs * g.y + b.y;
    o4.z = (a2 - mu) * rs * g.z + b.z;
    o4.w = (a3 - mu) * rs * g.w + b.w;
    *(float4*)(out + (size_t)t * 1024 + j4) = o4;
}

extern "C" void kernel_launch(void* const* d_in, const int* in_sizes, int n_in,
                              void* d_out, int out_size, void* d_ws, size_t ws_size,
                              hipStream_t stream) {
    const float* x     = (const float*)d_in[0];   // [2,2048,1024]
    const float* rw    = (const float*)d_in[1];   // [8,1024]
    const float* rb    = (const float*)d_in[2];   // [8]
    const float* W1    = (const float*)d_in[3];   // [8,1024,4096]
    const float* b1    = (const float*)d_in[4];   // [8,4096]
    const float* W2    = (const float*)d_in[5];   // [8,4096,1024]
    const float* b2    = (const float*)d_in[6];   // [8,1024]
    const float* gamma = (const float*)d_in[7];   // [1024]
    const float* beta  = (const float*)d_in[8];   // [1024]
    float* out = (float*)d_out;

    // workspace carve (256B aligned)
    char* p = (char*)d_ws;
    auto alloc = [&](size_t bytes) { char* r = p; p += (bytes + 255) & ~(size_t)255; return r; };
    int*   counts  = (int*)alloc(16 * sizeof(int));      // counts[0..7], cursors[8..15]
    int*   cursors = counts + 8;
    int*   offsets = (int*)alloc(9 * sizeof(int));
    int*   eidx    = (int*)alloc(8192 * sizeof(int));
    float* wgt     = (float*)alloc(8192 * sizeof(float));
    int*   pos_of  = (int*)alloc(8192 * sizeof(int));
    int*   rows    = (int*)alloc(8192 * sizeof(int));
    u16*   xb      = (u16*)alloc((size_t)4096 * 1024 * 2);
    u16*   W1t     = (u16*)alloc((size_t)8 * 4096 * 1024 * 2);   // 64MB; dead after gemm1
    u16*   W2t     = (u16*)alloc((size_t)8 * 1024 * 4096 * 2);
    u16*   hbuf    = (u16*)alloc((size_t)8192 * 4096 * 2);
    // yb = 4 bf16 partial buffers (4 x 16MB = 64MB) alias W1t (dead after gemm1)
    u16* yb = W1t;

    hipLaunchKernelGGL(k_init, dim3(1), dim3(64), 0, stream, counts);
    hipLaunchKernelGGL(k_pre, dim3(17408), dim3(256), 0, stream,
                       x, rw, rb, xb, eidx, wgt, counts, W1, W1t, W2, W2t);
    hipLaunchKernelGGL(k_place2, dim3(32), dim3(256), 0, stream,
                       eidx, counts, cursors, offsets, rows, pos_of);
    hipLaunchKernelGGL(k_gemm1, dim3(8192), dim3(256), 0, stream, xb, W1t, b1, hbuf, rows, offsets);
    hipLaunchKernelGGL(k_gemm2, dim3(8192), dim3(256), 0, stream, hbuf, W2t, b2, yb, offsets);
    hipLaunchKernelGGL(k_combine, dim3(4096), dim3(256), 0, stream, x, yb, pos_of, wgt, gamma, beta, out);
}

// Round 11
// 428.293 us; speedup vs baseline: 1.1104x; 1.0073x over previous
//
#include <hip/hip_runtime.h>
#include <hip/hip_bf16.h>

// MoE head: router(top2 of 8) -> compact -> GEMM1+GELU -> GEMM2(split-K x4) -> combine+residual+LN
// R11: transpose rewritten for BW: 256x128 tiles, 512-B segments both sides,
//      bf16 LDS [256][128] with word-XOR swizzle (conflict-free). Was 196us @1.4TB/s.
//      GEMMs/place/combine byte-identical to R10.

typedef unsigned short u16;
typedef unsigned int u32;
typedef __attribute__((ext_vector_type(4))) float f32x4;
typedef __attribute__((ext_vector_type(8))) short s16x8;
typedef __attribute__((ext_vector_type(4))) unsigned short u16x4;
typedef __attribute__((ext_vector_type(8))) unsigned short u16x8;

#define GLD16(gp, lp) __builtin_amdgcn_global_load_lds( \
    (const __attribute__((address_space(1))) void*)(gp), \
    (__attribute__((address_space(3))) void*)(lp), 16, 0, 0)

__device__ __forceinline__ u16 f2bf(float f) {
    union { float f; u32 u; } v; v.f = f;
    u32 u = v.u;
    return (u16)((u + 0x7fffu + ((u >> 16) & 1u)) >> 16);
}
__device__ __forceinline__ float bf2f(u16 h) {
    union { u32 u; float f; } v; v.u = ((u32)h) << 16; return v.f;
}

// fast GELU: v * sigmoid(1.59577v + 0.0713548v^3)
__device__ __forceinline__ float gelu_f(float v) {
    const float u = v * (0.7978845608f + 0.0356774081f * v * v);
    const float t = __expf(-2.0f * u);
    return v * __builtin_amdgcn_rcpf(1.0f + t);
}

// ---------------- K0: zero counts+cursors (16 ints) ----------------
__global__ void k_init(int* cc) { if (threadIdx.x < 16) cc[threadIdx.x] = 0; }

// ---------------- K1: fused router + weight transpose (3072 blocks) ----------------
// blocks 0..1023: router (4 tokens each) + x->bf16
// blocks 1024..2047: W1 [e][1024k][4096n] -> W1t [e][4096n][1024k], 256x128 tiles
// blocks 2048..3071: W2 [e][4096k][1024n] -> W2t [e][1024n][4096k], 256x128 tiles
__global__ __launch_bounds__(256) void k_pre(
    const float* __restrict__ x, const float* __restrict__ rw, const float* __restrict__ rb,
    u16* __restrict__ xb, int* __restrict__ eidx, float* __restrict__ wgt, int* __restrict__ counts,
    const float* __restrict__ W1, u16* __restrict__ W1t,
    const float* __restrict__ W2, u16* __restrict__ W2t)
{
    __shared__ u16 tl[256 * 128];   // 64KB; transpose tiles only
    const int id = blockIdx.x;
    const int tid = threadIdx.x;

    if (id >= 1024) {
        const float* s; u16* d; int R, C, r0, c0;
        if (id < 2048) {
            const int id2 = id - 1024;          // W1: 128 tiles/e (4 r-tiles x 32 c-tiles)
            const int e = id2 >> 7, rem = id2 & 127;
            const int rt = rem >> 5, ct = rem & 31;
            s = W1 + (size_t)e * 1024 * 4096; d = W1t + (size_t)e * 1024 * 4096;
            R = 1024; C = 4096; r0 = rt * 256; c0 = ct * 128;
        } else {
            const int id3 = id - 2048;          // W2: 128 tiles/e (16 r-tiles x 8 c-tiles)
            const int e = id3 >> 7, rem = id3 & 127;
            const int rt = rem >> 3, ct = rem & 7;
            s = W2 + (size_t)e * 4096 * 1024; d = W2t + (size_t)e * 4096 * 1024;
            R = 4096; C = 1024; r0 = rt * 256; c0 = ct * 128;
        }
        const int g = tid >> 5, ln = tid & 31;
        // read: 512-B row segments (32 lanes x float4); convert; swizzled b64 LDS store
        #pragma unroll 4
        for (int it = 0; it < 32; ++it) {
            const int r = it * 8 + g;
            const float4 v = *(const float4*)(s + (size_t)(r0 + r) * C + c0 + ln * 4);
            u16x4 pk;
            pk[0] = f2bf(v.x); pk[1] = f2bf(v.y); pk[2] = f2bf(v.z); pk[3] = f2bf(v.w);
            const int word = r * 32 + (ln ^ (r >> 3));
            *(u16x4*)(&tl[word * 4]) = pk;
        }
        __syncthreads();
        // write: 512-B column segments (32 lanes x u16x8); swizzled u16 gathers
        #pragma unroll 2
        for (int it = 0; it < 16; ++it) {
            const int c = it * 8 + g;
            const int cw = c >> 2, ce = c & 3;
            u16x8 o;
            #pragma unroll
            for (int j = 0; j < 8; ++j) {
                const int r = ln * 8 + j;
                const int word = r * 32 + (cw ^ (r >> 3));
                o[j] = tl[word * 4 + ce];
            }
            *(u16x8*)(d + (size_t)(c0 + c) * R + r0 + ln * 8) = o;
        }
        return;
    }

    // router path
    const int wav = tid >> 6, lane = tid & 63;
    const int t = id * 4 + wav;
    const float* xt = x + (size_t)t * 1024;
    float acc[8] = {0.f,0.f,0.f,0.f,0.f,0.f,0.f,0.f};
    #pragma unroll
    for (int c = 0; c < 4; c++) {
        const int base = c * 256 + lane * 4;
        const float4 xv = *(const float4*)(xt + base);
        ushort4 pk;
        pk.x = f2bf(xv.x); pk.y = f2bf(xv.y); pk.z = f2bf(xv.z); pk.w = f2bf(xv.w);
        *(ushort4*)(xb + (size_t)t * 1024 + base) = pk;
        #pragma unroll
        for (int e = 0; e < 8; e++) {
            const float4 wv = *(const float4*)(rw + e * 1024 + base);
            acc[e] += xv.x * wv.x + xv.y * wv.y + xv.z * wv.z + xv.w * wv.w;
        }
    }
    #pragma unroll
    for (int e = 0; e < 8; e++) {
        #pragma unroll
        for (int s = 32; s; s >>= 1) acc[e] += __shfl_xor(acc[e], s);
    }
    if (lane == 0) {
        float v0 = -3e38f, v1 = -3e38f; int i0 = 0, i1 = 0;
        #pragma unroll
        for (int e = 0; e < 8; e++) {
            const float l = acc[e] + rb[e];
            if (l > v0) { v1 = v0; i1 = i0; v0 = l; i0 = e; }
            else if (l > v1) { v1 = l; i1 = e; }
        }
        const float w0 = 1.0f / (1.0f + expf(v1 - v0));
        eidx[2 * t] = i0; eidx[2 * t + 1] = i1;
        wgt[2 * t] = w0; wgt[2 * t + 1] = 1.0f - w0;
        atomicAdd(&counts[i0], 1); atomicAdd(&counts[i1], 1);
    }
}

// ---------------- K2: place (prefix computed locally from counts; block 0 publishes offsets) ----------------
__global__ __launch_bounds__(256) void k_place2(
    const int* __restrict__ eidx, const int* __restrict__ counts, int* __restrict__ cursors,
    int* __restrict__ offsets, int* __restrict__ rows, int* __restrict__ pos_of)
{
    int base[8];
    int s = 0;
    #pragma unroll
    for (int e = 0; e < 8; e++) { base[e] = s; s += counts[e]; }
    if (blockIdx.x == 0 && threadIdx.x == 0) {
        #pragma unroll
        for (int e = 0; e < 8; e++) offsets[e] = base[e];
        offsets[8] = s;
    }
    const int a = blockIdx.x * 256 + threadIdx.x;   // 8192 assignments
    const int e = eidx[a];
    const int pos = base[e] + atomicAdd(&cursors[e], 1);
    rows[pos] = a >> 1;
    pos_of[a] = pos;
}

// shared GEMM macros: LDS [2][128][32] bf16 per operand, linear dest;
// source column pre-swizzled (chunk ^= (row>>1)&3), read offset swizzled to match.
#define STAGE_T(b, k0) { \
    char* ad = (char*)At + (b) * 8192 + wav * 1024; \
    char* bd = (char*)Bt + (b) * 8192 + wav * 1024; \
    GLD16(a_src0 + (k0), ad); \
    GLD16(a_src1 + (k0), ad + 4096); \
    GLD16(b_src0 + (k0), bd); \
    GLD16(b_src1 + (k0), bd + 4096); }

#define COMPUTE_T(b) { \
    const u16* Abp = Ab + (b) * 4096; \
    const u16* Bbp = Bb + (b) * 4096; \
    s16x8 af[4], bfr[4]; \
    _Pragma("unroll") \
    for (int i = 0; i < 4; i++) { \
        af[i]  = *(const s16x8*)(Abp + i * 512); \
        bfr[i] = *(const s16x8*)(Bbp + i * 512); \
    } \
    __builtin_amdgcn_s_setprio(1); \
    _Pragma("unroll") \
    for (int mi = 0; mi < 4; mi++) \
        _Pragma("unroll") \
        for (int ni = 0; ni < 4; ni++) \
            acc[mi][ni] = __builtin_amdgcn_mfma_f32_16x16x32_bf16(af[mi], bfr[ni], acc[mi][ni], 0, 0, 0); \
    __builtin_amdgcn_s_setprio(0); }

#define VMCNT4 asm volatile("s_waitcnt vmcnt(4)" ::: "memory")
#define VMCNT0 asm volatile("s_waitcnt vmcnt(0)" ::: "memory")
#define BAR __builtin_amdgcn_s_barrier()

// ---------------- K5: grouped GEMM1 + bias + fast GELU -> h (bf16) ----------------
// 8192 blocks flat; swz -> (e, x=n-tile of 32, y=row-tile of 32, y fastest)
__global__ __launch_bounds__(256, 4) void k_gemm1(
    const u16* __restrict__ xb, const u16* __restrict__ W1t, const float* __restrict__ b1,
    u16* __restrict__ hbuf, const int* __restrict__ rows, const int* __restrict__ offsets)
{
    const int fid = blockIdx.x;
    const int swz = (fid & 7) * 1024 + (fid >> 3);   // bijective, nwg=8192
    const int y = swz & 31, xx = (swz >> 5) & 31, e = swz >> 10;

    const int off = offsets[e], cnt = offsets[e + 1] - off;
    const int row0 = y * 128;
    if (row0 >= cnt) return;
    const int n0 = xx * 128;
    const int tid = threadIdx.x;
    const int lane = tid & 63, wav = tid >> 6, lane15 = lane & 15;

    __shared__ u16 At[2][128][32];
    __shared__ u16 Bt[2][128][32];

    const int ar0 = tid >> 2;
    const int cl8 = (((tid & 3) ^ ((tid >> 3) & 3))) * 8;   // swizzled source chunk
    const int t0 = rows[off + min(row0 + ar0, cnt - 1)];
    const int t1 = rows[off + min(row0 + ar0 + 64, cnt - 1)];
    const u16* a_src0 = xb + (size_t)t0 * 1024 + cl8;
    const u16* a_src1 = xb + (size_t)t1 * 1024 + cl8;
    const u16* b_src0 = W1t + ((size_t)e * 4096 + n0 + ar0) * 1024 + cl8;
    const u16* b_src1 = b_src0 + (size_t)64 * 1024;

    f32x4 acc[4][4] = {};
    const int wr = wav >> 1, wc = wav & 1;
    const int koff = ((lane >> 4) ^ ((lane >> 1) & 3)) * 8;  // swizzled read chunk
    const u16* Ab = &At[0][wr * 64 + lane15][koff];
    const u16* Bb = &Bt[0][wc * 64 + lane15][koff];

    STAGE_T(0, 0);
    int b = 0;
    for (int k0 = 32; k0 < 1024; k0 += 32) {
        STAGE_T(b ^ 1, k0);
        VMCNT4;             // current buffer's 4 loads landed (next 4 stay in flight)
        BAR;
        COMPUTE_T(b);
        BAR;                // all waves done reading buffer b
        b ^= 1;
    }
    VMCNT0;
    BAR;
    COMPUTE_T(b);

    const int rb4 = (lane >> 4) * 4;
    const int colbase = n0 + wc * 64 + lane15;
    float bias[4];
    #pragma unroll
    for (int ni = 0; ni < 4; ni++) bias[ni] = b1[e * 4096 + colbase + ni * 16];
    #pragma unroll
    for (int mi = 0; mi < 4; mi++) {
        #pragma unroll
        for (int j = 0; j < 4; j++) {
            const int lrow = wr * 64 + mi * 16 + rb4 + j;
            if (row0 + lrow < cnt) {
                const size_t gr = (size_t)(off + row0 + lrow);
                #pragma unroll
                for (int ni = 0; ni < 4; ni++) {
                    const float v = acc[mi][ni][j] + bias[ni];
                    hbuf[gr * 4096 + colbase + ni * 16] = f2bf(gelu_f(v));
                }
            }
        }
    }
}

// ---------------- K6: grouped GEMM2 (split-K x4) + bias -> yb[4] (bf16) ----------------
// 8192 blocks flat; swz -> (z = e*4+kq, x=n-tile of 8, y=row-tile of 32, y fastest)
__global__ __launch_bounds__(256, 4) void k_gemm2(
    const u16* __restrict__ hbuf, const u16* __restrict__ W2t, const float* __restrict__ b2,
    u16* __restrict__ yb, const int* __restrict__ offsets)
{
    const int fid = blockIdx.x;
    const int swz = (fid & 7) * 1024 + (fid >> 3);   // bijective, nwg=8192
    const int y = swz & 31, xx = (swz >> 5) & 7, z = swz >> 8;
    const int e = z >> 2, kq = z & 3;

    const int off = offsets[e], cnt = offsets[e + 1] - off;
    const int row0 = y * 128;
    if (row0 >= cnt) return;
    const int n0 = xx * 128;
    const int tid = threadIdx.x;
    const int lane = tid & 63, wav = tid >> 6, lane15 = lane & 15;
    const int kbase = kq * 1024;

    __shared__ u16 At[2][128][32];
    __shared__ u16 Bt[2][128][32];

    const int ar0 = tid >> 2;
    const int cl8 = (((tid & 3) ^ ((tid >> 3) & 3))) * 8;
    const u16* a_src0 = hbuf + (size_t)(off + min(row0 + ar0, cnt - 1)) * 4096 + kbase + cl8;
    const u16* a_src1 = hbuf + (size_t)(off + min(row0 + ar0 + 64, cnt - 1)) * 4096 + kbase + cl8;
    const u16* b_src0 = W2t + ((size_t)e * 1024 + n0 + ar0) * 4096 + kbase + cl8;
    const u16* b_src1 = b_src0 + (size_t)64 * 4096;

    f32x4 acc[4][4] = {};
    const int wr = wav >> 1, wc = wav & 1;
    const int koff = ((lane >> 4) ^ ((lane >> 1) & 3)) * 8;
    const u16* Ab = &At[0][wr * 64 + lane15][koff];
    const u16* Bb = &Bt[0][wc * 64 + lane15][koff];

    STAGE_T(0, 0);
    int b = 0;
    for (int k0 = 32; k0 < 1024; k0 += 32) {
        STAGE_T(b ^ 1, k0);
        VMCNT4;
        BAR;
        COMPUTE_T(b);
        BAR;
        b ^= 1;
    }
    VMCNT0;
    BAR;
    COMPUTE_T(b);

    u16* yy = yb + (size_t)kq * 8192 * 1024;
    const int rb4 = (lane >> 4) * 4;
    const int colbase = n0 + wc * 64 + lane15;
    float bias[4];
    #pragma unroll
    for (int ni = 0; ni < 4; ni++) bias[ni] = (kq == 0) ? b2[e * 1024 + colbase + ni * 16] : 0.f;
    #pragma unroll
    for (int mi = 0; mi < 4; mi++) {
        #pragma unroll
        for (int j = 0; j < 4; j++) {
            const int lrow = wr * 64 + mi * 16 + rb4 + j;
            if (row0 + lrow < cnt) {
                const size_t gr = (size_t)(off + row0 + lrow);
                #pragma unroll
                for (int ni = 0; ni < 4; ni++)
                    yy[gr * 1024 + colbase + ni * 16] = f2bf(acc[mi][ni][j] + bias[ni]);
            }
        }
    }
}

// ---------------- K7: combine (w0*sum4(y[p0]) + w1*sum4(y[p1]) + residual) + LayerNorm ----------------
__global__ __launch_bounds__(256) void k_combine(
    const float* __restrict__ x, const u16* __restrict__ yb,
    const int* __restrict__ pos_of, const float* __restrict__ wgt,
    const float* __restrict__ gamma, const float* __restrict__ beta,
    float* __restrict__ out)
{
    const int t = blockIdx.x;
    const int tid = threadIdx.x;
    const int p0 = pos_of[2 * t], p1 = pos_of[2 * t + 1];
    const float w0 = wgt[2 * t], w1 = wgt[2 * t + 1];
    const int j4 = tid * 4;
    const float4 xv = *(const float4*)(x + (size_t)t * 1024 + j4);
    float s0[4] = {0.f, 0.f, 0.f, 0.f};
    float s1[4] = {0.f, 0.f, 0.f, 0.f};
    #pragma unroll
    for (int kq = 0; kq < 4; kq++) {
        const u16* ybq = yb + (size_t)kq * 8192 * 1024;
        const ushort4 u0 = *(const ushort4*)(ybq + (size_t)p0 * 1024 + j4);
        const ushort4 u1 = *(const ushort4*)(ybq + (size_t)p1 * 1024 + j4);
        s0[0] += bf2f(u0.x); s0[1] += bf2f(u0.y); s0[2] += bf2f(u0.z); s0[3] += bf2f(u0.w);
        s1[0] += bf2f(u1.x); s1[1] += bf2f(u1.y); s1[2] += bf2f(u1.z); s1[3] += bf2f(u1.w);
    }
    float a0 = xv.x + w0 * s0[0] + w1 * s1[0];
    float a1 = xv.y + w0 * s0[1] + w1 * s1[1];
    float a2 = xv.z + w0 * s0[2] + w1 * s1[2];
    float a3 = xv.w + w0 * s0[3] + w1 * s1[3];
    float s = a0 + a1 + a2 + a3;
    float q = a0 * a0 + a1 * a1 + a2 * a2 + a3 * a3;
    #pragma unroll
    for (int o = 32; o; o >>= 1) { s += __shfl_xor(s, o); q += __shfl_xor(q, o); }
    __shared__ float ls[4], lq[4];
    const int wav = tid >> 6, lane = tid & 63;
    if (lane == 0) { ls[wav] = s; lq[wav] = q; }
    __syncthreads();
    s = ls[0] + ls[1] + ls[2] + ls[3];
    q = lq[0] + lq[1] + lq[2] + lq[3];
    const float mu = s * (1.0f / 1024.0f);
    const float var = q * (1.0f / 1024.0f) - mu * mu;
    const float rs = rsqrtf(var + 1e-5f);
    const float4 g = *(const float4*)(gamma + j4);
    const float4 b = *(const float4*)(beta + j4);
    float4 o4;
    o4.x = (a0 - mu) * rs * g.x + b.x;
    o4.y = (a1 - mu) * rs * g.y + b.y;
    o4.z = (a2 - mu) * rs * g.z + b.z;
    o4.w = (a3 - mu) * rs * g.w + b.w;
    *(float4*)(out + (size_t)t * 1024 + j4) = o4;
}

extern "C" void kernel_launch(void* const* d_in, const int* in_sizes, int n_in,
                              void* d_out, int out_size, void* d_ws, size_t ws_size,
                              hipStream_t stream) {
    const float* x     = (const float*)d_in[0];   // [2,2048,1024]
    const float* rw    = (const float*)d_in[1];   // [8,1024]
    const float* rb    = (const float*)d_in[2];   // [8]
    const float* W1    = (const float*)d_in[3];   // [8,1024,4096]
    const float* b1    = (const float*)d_in[4];   // [8,4096]
    const float* W2    = (const float*)d_in[5];   // [8,4096,1024]
    const float* b2    = (const float*)d_in[6];   // [8,1024]
    const float* gamma = (const float*)d_in[7];   // [1024]
    const float* beta  = (const float*)d_in[8];   // [1024]
    float* out = (float*)d_out;

    // workspace carve (256B aligned)
    char* p = (char*)d_ws;
    auto alloc = [&](size_t bytes) { char* r = p; p += (bytes + 255) & ~(size_t)255; return r; };
    int*   counts  = (int*)alloc(16 * sizeof(int));      // counts[0..7], cursors[8..15]
    int*   cursors = counts + 8;
    int*   offsets = (int*)alloc(9 * sizeof(int));
    int*   eidx    = (int*)alloc(8192 * sizeof(int));
    float* wgt     = (float*)alloc(8192 * sizeof(float));
    int*   pos_of  = (int*)alloc(8192 * sizeof(int));
    int*   rows    = (int*)alloc(8192 * sizeof(int));
    u16*   xb      = (u16*)alloc((size_t)4096 * 1024 * 2);
    u16*   W1t     = (u16*)alloc((size_t)8 * 4096 * 1024 * 2);   // 64MB; dead after gemm1
    u16*   W2t     = (u16*)alloc((size_t)8 * 1024 * 4096 * 2);
    u16*   hbuf    = (u16*)alloc((size_t)8192 * 4096 * 2);
    // yb = 4 bf16 partial buffers (4 x 16MB = 64MB) alias W1t (dead after gemm1)
    u16* yb = W1t;

    hipLaunchKernelGGL(k_init, dim3(1), dim3(64), 0, stream, counts);
    hipLaunchKernelGGL(k_pre, dim3(3072), dim3(256), 0, stream,
                       x, rw, rb, xb, eidx, wgt, counts, W1, W1t, W2, W2t);
    hipLaunchKernelGGL(k_place2, dim3(32), dim3(256), 0, stream,
                       eidx, counts, cursors, offsets, rows, pos_of);
    hipLaunchKernelGGL(k_gemm1, dim3(8192), dim3(256), 0, stream, xb, W1t, b1, hbuf, rows, offsets);
    hipLaunchKernelGGL(k_gemm2, dim3(8192), dim3(256), 0, stream, hbuf, W2t, b2, yb, offsets);
    hipLaunchKernelGGL(k_combine, dim3(4096), dim3(256), 0, stream, x, yb, pos_of, wgt, gamma, beta, out);
}